// Round 2
// baseline (2994.090 us; speedup 1.0000x reference)
//
#include <hip/hip_runtime.h>
#include <math.h>

// ---------------------------------------------------------------------------
// MaskingDecoder: B=4, NQ=4096, NL=1024, DIM=512, HEADS=8, DH=64, hid=2048
// fp32, chunked pipeline. Workspace (floats):
//   shared: cn 4096x512 | kb 4096x512 | vb 4096x512 | tabl 4096x32
//   chunk : qtokC CQx512 | xnC CQx512 | qC CQx512 | agC CQx2048 | tabqC CQx32
// worst case CQ=4096: 84.9 MB. CQ halves until it fits ws_size.
// ---------------------------------------------------------------------------

// ---------------- rope table: 16 (cos,sin) pairs per row --------------------
__global__ void k_rope_tab16(const float* __restrict__ t, float* __restrict__ tab,
                             const int n)
{
    const int idx = blockIdx.x * 256 + threadIdx.x;
    if (idx >= n * 16) return;
    const int r = idx >> 4, i = idx & 15;
    const float b0 = (float)(1e-4 / 2.0627);
    const float a0 = (float)(2.0 * 3.14159265358979323846 / 1e-4);
    const float invf = a0 * (float)pow((double)b0, (double)i * (1.0 / 16.0));
    const float ang = t[r] * invf;
    float sn, cs;
    sincosf(ang, &sn, &cs);
    tab[((size_t)r << 5) + (i << 1)]     = cs;
    tab[((size_t)r << 5) + (i << 1) + 1] = sn;
}

// ---------------- qtok build + layernorm ------------------------------------
__global__ __launch_bounds__(128) void k_qtok_ln(
    const int* __restrict__ qidx, const float* __restrict__ uemb,
    const float* __restrict__ vpb, const float* __restrict__ w,
    const float* __restrict__ bb, float* __restrict__ qtok, float* __restrict__ xn)
{
    const int r = blockIdx.x, tid = threadIdx.x, c0 = tid << 2;
    float4 x;
    if (c0 < 256) {
        x = *(const float4*)&vpb[c0];
    } else {
        const int u = qidx[r];
        x = *(const float4*)&uemb[(size_t)u * 256 + (c0 - 256)];
    }
    *(float4*)&qtok[(size_t)r * 512 + c0] = x;
    float s  = x.x + x.y + x.z + x.w;
    float s2 = x.x * x.x + x.y * x.y + x.z * x.z + x.w * x.w;
#pragma unroll
    for (int o = 32; o > 0; o >>= 1) { s += __shfl_down(s, o); s2 += __shfl_down(s2, o); }
    __shared__ float buf[4];
    if ((tid & 63) == 0) { buf[(tid >> 6) << 1] = s; buf[((tid >> 6) << 1) + 1] = s2; }
    __syncthreads();
    s = buf[0] + buf[2]; s2 = buf[1] + buf[3];
    const float mu = s * (1.f / 512.f);
    const float rs = rsqrtf(s2 * (1.f / 512.f) - mu * mu + 1e-5f);
    const float4 w4 = *(const float4*)&w[c0];
    const float4 b4 = *(const float4*)&bb[c0];
    float4 y;
    y.x = (x.x - mu) * rs * w4.x + b4.x;
    y.y = (x.y - mu) * rs * w4.y + b4.y;
    y.z = (x.z - mu) * rs * w4.z + b4.z;
    y.w = (x.w - mu) * rs * w4.w + b4.w;
    *(float4*)&xn[(size_t)r * 512 + c0] = y;
}

// ---------------- generic layernorm (512 wide) ------------------------------
__global__ __launch_bounds__(128) void k_ln(
    const float* __restrict__ in, const float* __restrict__ w,
    const float* __restrict__ bb, float* __restrict__ outp)
{
    const int r = blockIdx.x, tid = threadIdx.x, c0 = tid << 2;
    const float4 x = *(const float4*)&in[(size_t)r * 512 + c0];
    float s  = x.x + x.y + x.z + x.w;
    float s2 = x.x * x.x + x.y * x.y + x.z * x.z + x.w * x.w;
#pragma unroll
    for (int o = 32; o > 0; o >>= 1) { s += __shfl_down(s, o); s2 += __shfl_down(s2, o); }
    __shared__ float buf[4];
    if ((tid & 63) == 0) { buf[(tid >> 6) << 1] = s; buf[((tid >> 6) << 1) + 1] = s2; }
    __syncthreads();
    s = buf[0] + buf[2]; s2 = buf[1] + buf[3];
    const float mu = s * (1.f / 512.f);
    const float rs = rsqrtf(s2 * (1.f / 512.f) - mu * mu + 1e-5f);
    const float4 w4 = *(const float4*)&w[c0];
    const float4 b4 = *(const float4*)&bb[c0];
    float4 y;
    y.x = (x.x - mu) * rs * w4.x + b4.x;
    y.y = (x.y - mu) * rs * w4.y + b4.y;
    y.z = (x.z - mu) * rs * w4.z + b4.z;
    y.w = (x.w - mu) * rs * w4.w + b4.w;
    *(float4*)&outp[(size_t)r * 512 + c0] = y;
}

// ---------------- tiled fp32 GEMM: C[m,n] = sum_k A[m,k]*W[n,k] --------------
// EPI 0: rope(tab), write d0                         [q projection]
// EPI 1: rope(tab), col<512 -> d0, col>=512 -> d1    [kv projection]
// EPI 2: d0[r,c] = acc + bias[c] + res[r,c]  (N==512, d0/res distinct)
template <int EPI>
__global__ __launch_bounds__(256) void k_gemm(
    const float* __restrict__ A, const float* __restrict__ W,
    const int M, const int N, const int K,
    float* __restrict__ d0, float* __restrict__ d1,
    const float* __restrict__ bias, const float* __restrict__ res,
    const float* __restrict__ tab)
{
    __shared__ float As[16][64];
    __shared__ float Ws[16][64];
    const int bm = blockIdx.y << 6, bn = blockIdx.x << 6;
    const int tid = threadIdx.x;
    const int lr = tid >> 2, lk = (tid & 3) << 2;
    const int tx = tid & 15, ty = tid >> 4;
    const float* Ap = A + (size_t)(bm + lr) * K + lk;
    const float* Wp = W + (size_t)(bn + lr) * K + lk;
    float acc[4][4] = {};
    for (int k0 = 0; k0 < K; k0 += 16) {
        const float4 av = *(const float4*)(Ap + k0);
        const float4 wv = *(const float4*)(Wp + k0);
        __syncthreads();
        As[lk + 0][lr] = av.x; As[lk + 1][lr] = av.y; As[lk + 2][lr] = av.z; As[lk + 3][lr] = av.w;
        Ws[lk + 0][lr] = wv.x; Ws[lk + 1][lr] = wv.y; Ws[lk + 2][lr] = wv.z; Ws[lk + 3][lr] = wv.w;
        __syncthreads();
#pragma unroll
        for (int kk = 0; kk < 16; ++kk) {
            const float4 a4 = *(const float4*)&As[kk][ty << 2];
            const float4 w4 = *(const float4*)&Ws[kk][tx << 2];
            const float a[4] = {a4.x, a4.y, a4.z, a4.w};
            const float w[4] = {w4.x, w4.y, w4.z, w4.w};
#pragma unroll
            for (int i = 0; i < 4; i++)
#pragma unroll
                for (int j = 0; j < 4; j++)
                    acc[i][j] = fmaf(a[i], w[j], acc[i][j]);
        }
    }
#pragma unroll
    for (int i = 0; i < 4; i++) {
        const int r = bm + (ty << 2) + i;
        if (EPI == 2) {
#pragma unroll
            for (int j = 0; j < 4; j++) {
                const int c = bn + (tx << 2) + j;
                d0[(size_t)r * 512 + c] = acc[i][j] + bias[c] + res[(size_t)r * 512 + c];
            }
        } else {
#pragma unroll
            for (int j = 0; j < 4; j += 2) {
                const int c = bn + (tx << 2) + j;
                const int ii = (c & 63) >> 1;
                const float x0 = acc[i][j], x1 = acc[i][j + 1];
                float y0 = x0, y1 = x1;
                if (ii < 16) {
                    const float cc = tab[((size_t)r << 5) + (ii << 1)];
                    const float ss = tab[((size_t)r << 5) + (ii << 1) + 1];
                    y0 = x0 * cc - x1 * ss;
                    y1 = x1 * cc + x0 * ss;
                }
                if (EPI == 0) {
                    d0[(size_t)r * 512 + c]     = y0;
                    d0[(size_t)r * 512 + c + 1] = y1;
                } else {
                    if (c < 512) {
                        d0[(size_t)r * 512 + c]     = y0;
                        d0[(size_t)r * 512 + c + 1] = y1;
                    } else {
                        d1[(size_t)r * 512 + (c - 512)]     = y0;
                        d1[(size_t)r * 512 + (c - 512) + 1] = y1;
                    }
                }
            }
        }
    }
}

// ---------------- FFN1: dual GEMM + exact gelu gate -------------------------
__global__ __launch_bounds__(256) void k_ffn1(
    const float* __restrict__ A, const float* __restrict__ W1,
    const float* __restrict__ b1, float* __restrict__ ag, const int K)
{
    __shared__ float As[16][64];
    __shared__ float Wa[16][64];
    __shared__ float Wg[16][64];
    const int bm = blockIdx.y << 6, bn = blockIdx.x << 6;
    const int tid = threadIdx.x;
    const int lr = tid >> 2, lk = (tid & 3) << 2;
    const int tx = tid & 15, ty = tid >> 4;
    const float* Ap  = A  + (size_t)(bm + lr) * K + lk;
    const float* Wap = W1 + (size_t)(bn + lr) * K + lk;
    const float* Wgp = W1 + (size_t)(bn + 2048 + lr) * K + lk;
    float aa[4][4] = {}, gg[4][4] = {};
    for (int k0 = 0; k0 < K; k0 += 16) {
        const float4 av  = *(const float4*)(Ap + k0);
        const float4 wav = *(const float4*)(Wap + k0);
        const float4 wgv = *(const float4*)(Wgp + k0);
        __syncthreads();
        As[lk + 0][lr] = av.x;  As[lk + 1][lr] = av.y;  As[lk + 2][lr] = av.z;  As[lk + 3][lr] = av.w;
        Wa[lk + 0][lr] = wav.x; Wa[lk + 1][lr] = wav.y; Wa[lk + 2][lr] = wav.z; Wa[lk + 3][lr] = wav.w;
        Wg[lk + 0][lr] = wgv.x; Wg[lk + 1][lr] = wgv.y; Wg[lk + 2][lr] = wgv.z; Wg[lk + 3][lr] = wgv.w;
        __syncthreads();
#pragma unroll
        for (int kk = 0; kk < 16; ++kk) {
            const float4 a4  = *(const float4*)&As[kk][ty << 2];
            const float4 wa4 = *(const float4*)&Wa[kk][tx << 2];
            const float4 wg4 = *(const float4*)&Wg[kk][tx << 2];
            const float a[4]  = {a4.x, a4.y, a4.z, a4.w};
            const float wa[4] = {wa4.x, wa4.y, wa4.z, wa4.w};
            const float wg[4] = {wg4.x, wg4.y, wg4.z, wg4.w};
#pragma unroll
            for (int i = 0; i < 4; i++)
#pragma unroll
                for (int j = 0; j < 4; j++) {
                    aa[i][j] = fmaf(a[i], wa[j], aa[i][j]);
                    gg[i][j] = fmaf(a[i], wg[j], gg[i][j]);
                }
        }
    }
#pragma unroll
    for (int i = 0; i < 4; i++) {
        const int r = bm + (ty << 2) + i;
#pragma unroll
        for (int j = 0; j < 4; j++) {
            const int c = bn + (tx << 2) + j;
            const float a = aa[i][j] + b1[c];
            const float g = gg[i][j] + b1[c + 2048];
            const float ge = 0.5f * g * (1.f + erff(g * 0.70710678118654752f));
            ag[(size_t)r * 2048 + c] = a * ge;
        }
    }
}

// ---------------- attention: flash-style, 32 q-rows per block ---------------
// q/tab/out are chunk-local (rows 0..CQ); k/v are global with batch b.
__global__ __launch_bounds__(256) void k_attn(
    const float* __restrict__ q, const float* __restrict__ k, const float* __restrict__ v,
    const float* __restrict__ tab, float* __restrict__ out, const int b)
{
    __shared__ float qs[32][64];
    __shared__ float ks[64][64];
    __shared__ float vs[64][64];
    const int h = blockIdx.y;
    const int q0 = blockIdx.x << 5;
    const int tid = threadIdx.x;
    for (int f = tid; f < 512; f += 256) {
        const int row = f >> 4, col = (f & 15) << 2;
        *(float4*)&qs[row][col] =
            *(const float4*)&q[((size_t)(q0 + row)) * 512 + h * 64 + col];
    }
    const int ri = tid >> 3, l8 = tid & 7, ds = l8 << 3;
    float m = -INFINITY, l = 0.f;
    float acc[8] = {0, 0, 0, 0, 0, 0, 0, 0};
    for (int kc = 0; kc < 16; ++kc) {
        __syncthreads();
        for (int f = tid; f < 1024; f += 256) {
            const int row = f >> 4, col = (f & 15) << 2;
            const size_t g = ((size_t)(b * 1024 + (kc << 6) + row)) * 512 + h * 64 + col;
            *(float4*)&ks[row][col] = *(const float4*)&k[g];
            *(float4*)&vs[row][col] = *(const float4*)&v[g];
        }
        __syncthreads();
        float sc[8] = {0, 0, 0, 0, 0, 0, 0, 0};
#pragma unroll
        for (int d0 = 0; d0 < 64; d0 += 4) {
            const int d = (d0 + ds) & 63;  // skew so lanes hit different banks
            const float4 qv = *(const float4*)&qs[ri][d];
#pragma unroll
            for (int jj = 0; jj < 8; ++jj) {
                const float4 kv = *(const float4*)&ks[ds + jj][d];
                sc[jj] += qv.x * kv.x + qv.y * kv.y + qv.z * kv.z + qv.w * kv.w;
            }
        }
        float cm = -INFINITY;
#pragma unroll
        for (int jj = 0; jj < 8; ++jj) { sc[jj] *= 0.125f; cm = fmaxf(cm, sc[jj]); }
#pragma unroll
        for (int o = 1; o < 8; o <<= 1) cm = fmaxf(cm, __shfl_xor(cm, o));
        const float mnew = fmaxf(m, cm);
        const float scal = expf(m - mnew);
        float pv[8]; float psum = 0.f;
#pragma unroll
        for (int jj = 0; jj < 8; ++jj) { pv[jj] = expf(sc[jj] - mnew); psum += pv[jj]; }
#pragma unroll
        for (int o = 1; o < 8; o <<= 1) psum += __shfl_xor(psum, o);
        l = l * scal + psum;
        m = mnew;
#pragma unroll
        for (int d = 0; d < 8; ++d) acc[d] *= scal;
        const int baseLane = (tid & 63) & ~7;
#pragma unroll
        for (int js = 0; js < 8; ++js) {
#pragma unroll
            for (int j = 0; j < 8; ++j) {
                const float p = __shfl(pv[j], baseLane + js, 64);
                const int kj = (js << 3) + j;
                const float4 v0 = *(const float4*)&vs[kj][ds];
                const float4 v1 = *(const float4*)&vs[kj][ds + 4];
                acc[0] = fmaf(p, v0.x, acc[0]);
                acc[1] = fmaf(p, v0.y, acc[1]);
                acc[2] = fmaf(p, v0.z, acc[2]);
                acc[3] = fmaf(p, v0.w, acc[3]);
                acc[4] = fmaf(p, v1.x, acc[4]);
                acc[5] = fmaf(p, v1.y, acc[5]);
                acc[6] = fmaf(p, v1.z, acc[6]);
                acc[7] = fmaf(p, v1.w, acc[7]);
            }
        }
    }
    const float invl = 1.f / l;
    const int rg = q0 + ri;
    float res[8];
#pragma unroll
    for (int pp = 0; pp < 4; ++pp) {
        const float x0 = acc[2 * pp] * invl, x1 = acc[2 * pp + 1] * invl;
        const int ii = (ds >> 1) + pp;
        float y0 = x0, y1 = x1;
        if (ii < 16) {
            const float cc = tab[((size_t)rg << 5) + (ii << 1)];
            const float sn = tab[((size_t)rg << 5) + (ii << 1) + 1];
            y0 = x0 * cc + x1 * sn;   // inverse rotation
            y1 = x1 * cc - x0 * sn;
        }
        res[2 * pp]     = y0;
        res[2 * pp + 1] = y1;
    }
    float* op = &out[(size_t)rg * 512 + h * 64 + ds];
    *(float4*)&op[0] = make_float4(res[0], res[1], res[2], res[3]);
    *(float4*)&op[4] = make_float4(res[4], res[5], res[6], res[7]);
}

// ---------------- final: LN + dot with wproj --------------------------------
__global__ __launch_bounds__(128) void k_final(
    const float* __restrict__ dec, const float* __restrict__ w,
    const float* __restrict__ bb, const float* __restrict__ wproj,
    const float* __restrict__ bproj, float* __restrict__ out)
{
    const int r = blockIdx.x, tid = threadIdx.x, c0 = tid << 2;
    const float4 x = *(const float4*)&dec[(size_t)r * 512 + c0];
    float s  = x.x + x.y + x.z + x.w;
    float s2 = x.x * x.x + x.y * x.y + x.z * x.z + x.w * x.w;
#pragma unroll
    for (int o = 32; o > 0; o >>= 1) { s += __shfl_down(s, o); s2 += __shfl_down(s2, o); }
    __shared__ float buf[4];
    if ((tid & 63) == 0) { buf[(tid >> 6) << 1] = s; buf[((tid >> 6) << 1) + 1] = s2; }
    __syncthreads();
    s = buf[0] + buf[2]; s2 = buf[1] + buf[3];
    const float mu = s * (1.f / 512.f);
    const float rs = rsqrtf(s2 * (1.f / 512.f) - mu * mu + 1e-5f);
    const float4 w4 = *(const float4*)&w[c0];
    const float4 b4 = *(const float4*)&bb[c0];
    const float4 p4 = *(const float4*)&wproj[c0];
    float part = ((x.x - mu) * rs * w4.x + b4.x) * p4.x
               + ((x.y - mu) * rs * w4.y + b4.y) * p4.y
               + ((x.z - mu) * rs * w4.z + b4.z) * p4.z
               + ((x.w - mu) * rs * w4.w + b4.w) * p4.w;
#pragma unroll
    for (int o = 32; o > 0; o >>= 1) part += __shfl_down(part, o);
    __shared__ float buf2[2];
    if ((tid & 63) == 0) buf2[tid >> 6] = part;
    __syncthreads();
    if (tid == 0) out[r] = buf2[0] + buf2[1] + bproj[0];
}

// ---------------------------------------------------------------------------
extern "C" void kernel_launch(void* const* d_in, const int* in_sizes, int n_in,
                              void* d_out, int out_size, void* d_ws, size_t ws_size,
                              hipStream_t stream)
{
    (void)in_sizes; (void)n_in; (void)out_size;
    const float* enc  = (const float*)d_in[0];
    const float* lts  = (const float*)d_in[1];
    const int*   qidx = (const int*)  d_in[2];
    const float* qts  = (const float*)d_in[3];
    const float* uemb = (const float*)d_in[4];
    const float* vpb  = (const float*)d_in[6];
    const float* canw = (const float*)d_in[7];
    const float* canb = (const float*)d_in[8];
    const float* ccw  = (const float*)d_in[9];
    const float* ccb  = (const float*)d_in[10];
    const float* wq   = (const float*)d_in[11];
    const float* wkv  = (const float*)d_in[12];
    const float* wo   = (const float*)d_in[13];
    const float* bo   = (const float*)d_in[14];
    const float* flnw = (const float*)d_in[15];
    const float* flnb = (const float*)d_in[16];
    const float* w1   = (const float*)d_in[17];
    const float* b1   = (const float*)d_in[18];
    const float* w2   = (const float*)d_in[19];
    const float* b2   = (const float*)d_in[20];
    const float* olnw = (const float*)d_in[21];
    const float* olnb = (const float*)d_in[22];
    const float* wpj  = (const float*)d_in[23];
    const float* bpj  = (const float*)d_in[24];
    float* outp = (float*)d_out;

    // choose chunk size CQ (q rows per batch-chunk) so the footprint fits ws
    const size_t SHARED = 3u * 2097152u + 131072u;              // cn,kb,vb,tabl
    int CQ = 4096;
    while (CQ > 64 && (SHARED + (size_t)CQ * (512 * 3 + 2048 + 32)) * 4 > ws_size)
        CQ >>= 1;

    float* ws    = (float*)d_ws;
    float* cn    = ws;                       // 4096*512
    float* kb    = cn + 2097152;             // 4096*512
    float* vb    = kb + 2097152;             // 4096*512
    float* tabl  = vb + 2097152;             // 4096*32
    float* qtokC = tabl + 131072;            // CQ*512   (later: ln_dec)
    float* xnC   = qtokC + (size_t)CQ * 512; // CQ*512   (later: attn-out, dec-final)
    float* qC    = xnC + (size_t)CQ * 512;   // CQ*512   (later: dec2)
    float* agC   = qC + (size_t)CQ * 512;    // CQ*2048
    float* tabqC = agC + (size_t)CQ * 2048;  // CQ*32

    // shared phase: latent rope tab, ctx LN, K/V projection (+rope)
    k_rope_tab16<<<(4096 * 16 + 255) / 256, 256, 0, stream>>>(lts, tabl, 4096);
    k_ln<<<4096, 128, 0, stream>>>(enc, ccw, ccb, cn);
    k_gemm<1><<<dim3(16, 64), 256, 0, stream>>>(cn, wkv, 4096, 1024, 512,
                                                kb, vb, nullptr, nullptr, tabl);

    for (int b = 0; b < 4; ++b) {
        for (int g0 = 0; g0 < 4096; g0 += CQ) {
            const int rowbase = b * 4096 + g0;
            k_rope_tab16<<<(CQ * 16 + 255) / 256, 256, 0, stream>>>(qts + rowbase, tabqC, CQ);
            k_qtok_ln<<<CQ, 128, 0, stream>>>(qidx + rowbase, uemb, vpb, canw, canb,
                                              qtokC, xnC);
            k_gemm<0><<<dim3(8, CQ / 64), 256, 0, stream>>>(xnC, wq, CQ, 512, 512,
                                                            qC, nullptr, nullptr, nullptr, tabqC);
            k_attn<<<dim3(CQ / 32, 8), 256, 0, stream>>>(qC, kb, vb, tabqC, xnC, b);
            // dec2 = qtok + attn@wo.T + bo   (dec2 -> qC region, all distinct)
            k_gemm<2><<<dim3(8, CQ / 64), 256, 0, stream>>>(xnC, wo, CQ, 512, 512,
                                                            qC, nullptr, bo, qtokC, nullptr);
            // ln_dec -> qtokC region
            k_ln<<<CQ, 128, 0, stream>>>(qC, flnw, flnb, qtokC);
            k_ffn1<<<dim3(32, CQ / 64), 256, 0, stream>>>(qtokC, w1, b1, agC, 512);
            // dec_final = dec2 + ag@w2.T + b2 -> xnC region (distinct from res=qC)
            k_gemm<2><<<dim3(8, CQ / 64), 256, 0, stream>>>(agC, w2, CQ, 512, 2048,
                                                            xnC, nullptr, b2, qC, nullptr);
            k_final<<<CQ, 128, 0, stream>>>(xnC, olnw, olnb, wpj, bpj, outp + rowbase);
        }
    }
}

// Round 3
// 904.189 us; speedup vs baseline: 3.3114x; 3.3114x over previous
//
#include <hip/hip_runtime.h>
#include <math.h>

// ---------------------------------------------------------------------------
// MaskingDecoder bf16-MFMA: B=4, NQ=4096, NL=1024, DIM=512, HEADS=8, DH=64
// All GEMMs: 128x128 tile, 4 waves, 16x16x32_bf16 MFMA, fp32 accum.
// Attention: LDS-free, swapped QK^T, in-register P^T, 16x16x16 PV.
// ---------------------------------------------------------------------------

typedef unsigned short u16;
typedef __attribute__((ext_vector_type(8))) short bf16x8;
typedef __attribute__((ext_vector_type(4))) short bf16x4;
typedef __attribute__((ext_vector_type(4))) float f32x4;

__device__ __forceinline__ u16 f2b(float x) {
    union { float f; unsigned u; } v; v.f = x;
    unsigned r = v.u + 0x7fffu + ((v.u >> 16) & 1u);
    return (u16)(r >> 16);
}
__device__ __forceinline__ float b2f(u16 h) {
    union { unsigned u; float f; } v; v.u = ((unsigned)h) << 16;
    return v.f;
}
__device__ __forceinline__ f32x4 mfma32(bf16x8 a, bf16x8 b, f32x4 c) {
    return __builtin_amdgcn_mfma_f32_16x16x32_bf16(a, b, c, 0, 0, 0);
}
__device__ __forceinline__ f32x4 mfma16(bf16x4 a, bf16x4 b, f32x4 c) {
    asm("v_mfma_f32_16x16x16_bf16 %0, %1, %2, %0" : "+v"(c) : "v"(a), "v"(b));
    return c;
}

// ---------------- f32 -> bf16 weight convert --------------------------------
__global__ __launch_bounds__(256) void k_cvt(const float* __restrict__ in,
                                             u16* __restrict__ out, const int n)
{
    const int i = (blockIdx.x * 256 + threadIdx.x) * 4;
    if (i >= n) return;
    const float4 v = *(const float4*)&in[i];
    ushort4 o;
    o.x = f2b(v.x); o.y = f2b(v.y); o.z = f2b(v.z); o.w = f2b(v.w);
    *(ushort4*)&out[i] = o;
}

// ---------------- rope table: 16 (cos,sin) pairs per row --------------------
__global__ void k_rope_tab16(const float* __restrict__ t, float* __restrict__ tab,
                             const int n)
{
    const int idx = blockIdx.x * 256 + threadIdx.x;
    if (idx >= n * 16) return;
    const int r = idx >> 4, i = idx & 15;
    const float b0 = (float)(1e-4 / 2.0627);
    const float a0 = (float)(2.0 * 3.14159265358979323846 / 1e-4);
    const float invf = a0 * (float)pow((double)b0, (double)i * (1.0 / 16.0));
    const float ang = t[r] * invf;
    float sn, cs;
    sincosf(ang, &sn, &cs);
    tab[((size_t)r << 5) + (i << 1)]     = cs;
    tab[((size_t)r << 5) + (i << 1) + 1] = sn;
}

// ---------------- qtok build + layernorm -> bf16 ----------------------------
__global__ __launch_bounds__(128) void k_qtok_ln(
    const int* __restrict__ qidx, const float* __restrict__ uemb,
    const float* __restrict__ vpb, const float* __restrict__ w,
    const float* __restrict__ bb, u16* __restrict__ qtok, u16* __restrict__ xn)
{
    const int r = blockIdx.x, tid = threadIdx.x, c0 = tid << 2;
    float4 x;
    if (c0 < 256) {
        x = *(const float4*)&vpb[c0];
    } else {
        const int u = qidx[r];
        x = *(const float4*)&uemb[(size_t)u * 256 + (c0 - 256)];
    }
    ushort4 qo;
    qo.x = f2b(x.x); qo.y = f2b(x.y); qo.z = f2b(x.z); qo.w = f2b(x.w);
    *(ushort4*)&qtok[(size_t)r * 512 + c0] = qo;
    float s  = x.x + x.y + x.z + x.w;
    float s2 = x.x * x.x + x.y * x.y + x.z * x.z + x.w * x.w;
#pragma unroll
    for (int o = 32; o > 0; o >>= 1) { s += __shfl_down(s, o); s2 += __shfl_down(s2, o); }
    __shared__ float buf[4];
    if ((tid & 63) == 0) { buf[(tid >> 6) << 1] = s; buf[((tid >> 6) << 1) + 1] = s2; }
    __syncthreads();
    s = buf[0] + buf[2]; s2 = buf[1] + buf[3];
    const float mu = s * (1.f / 512.f);
    const float rs = rsqrtf(s2 * (1.f / 512.f) - mu * mu + 1e-5f);
    const float4 w4 = *(const float4*)&w[c0];
    const float4 b4 = *(const float4*)&bb[c0];
    ushort4 yo;
    yo.x = f2b((x.x - mu) * rs * w4.x + b4.x);
    yo.y = f2b((x.y - mu) * rs * w4.y + b4.y);
    yo.z = f2b((x.z - mu) * rs * w4.z + b4.z);
    yo.w = f2b((x.w - mu) * rs * w4.w + b4.w);
    *(ushort4*)&xn[(size_t)r * 512 + c0] = yo;
}

// ---------------- layernorm f32-in -> bf16-out ------------------------------
__global__ __launch_bounds__(128) void k_ln_f(
    const float* __restrict__ in, const float* __restrict__ w,
    const float* __restrict__ bb, u16* __restrict__ outp)
{
    const int r = blockIdx.x, tid = threadIdx.x, c0 = tid << 2;
    const float4 x = *(const float4*)&in[(size_t)r * 512 + c0];
    float s  = x.x + x.y + x.z + x.w;
    float s2 = x.x * x.x + x.y * x.y + x.z * x.z + x.w * x.w;
#pragma unroll
    for (int o = 32; o > 0; o >>= 1) { s += __shfl_down(s, o); s2 += __shfl_down(s2, o); }
    __shared__ float buf[4];
    if ((tid & 63) == 0) { buf[(tid >> 6) << 1] = s; buf[((tid >> 6) << 1) + 1] = s2; }
    __syncthreads();
    s = buf[0] + buf[2]; s2 = buf[1] + buf[3];
    const float mu = s * (1.f / 512.f);
    const float rs = rsqrtf(s2 * (1.f / 512.f) - mu * mu + 1e-5f);
    const float4 w4 = *(const float4*)&w[c0];
    const float4 b4 = *(const float4*)&bb[c0];
    ushort4 yo;
    yo.x = f2b((x.x - mu) * rs * w4.x + b4.x);
    yo.y = f2b((x.y - mu) * rs * w4.y + b4.y);
    yo.z = f2b((x.z - mu) * rs * w4.z + b4.z);
    yo.w = f2b((x.w - mu) * rs * w4.w + b4.w);
    *(ushort4*)&outp[(size_t)r * 512 + c0] = yo;
}

// ---------------- layernorm bf16-in -> bf16-out -----------------------------
__global__ __launch_bounds__(128) void k_ln_h(
    const u16* __restrict__ in, const float* __restrict__ w,
    const float* __restrict__ bb, u16* __restrict__ outp)
{
    const int r = blockIdx.x, tid = threadIdx.x, c0 = tid << 2;
    const ushort4 xi = *(const ushort4*)&in[(size_t)r * 512 + c0];
    float4 x;
    x.x = b2f(xi.x); x.y = b2f(xi.y); x.z = b2f(xi.z); x.w = b2f(xi.w);
    float s  = x.x + x.y + x.z + x.w;
    float s2 = x.x * x.x + x.y * x.y + x.z * x.z + x.w * x.w;
#pragma unroll
    for (int o = 32; o > 0; o >>= 1) { s += __shfl_down(s, o); s2 += __shfl_down(s2, o); }
    __shared__ float buf[4];
    if ((tid & 63) == 0) { buf[(tid >> 6) << 1] = s; buf[((tid >> 6) << 1) + 1] = s2; }
    __syncthreads();
    s = buf[0] + buf[2]; s2 = buf[1] + buf[3];
    const float mu = s * (1.f / 512.f);
    const float rs = rsqrtf(s2 * (1.f / 512.f) - mu * mu + 1e-5f);
    const float4 w4 = *(const float4*)&w[c0];
    const float4 b4 = *(const float4*)&bb[c0];
    ushort4 yo;
    yo.x = f2b((x.x - mu) * rs * w4.x + b4.x);
    yo.y = f2b((x.y - mu) * rs * w4.y + b4.y);
    yo.z = f2b((x.z - mu) * rs * w4.z + b4.z);
    yo.w = f2b((x.w - mu) * rs * w4.w + b4.w);
    *(ushort4*)&outp[(size_t)r * 512 + c0] = yo;
}

// ---------------- MFMA GEMM: C[m,n] = sum_k A[m,k]*W[n,k] -------------------
// 128x128 tile, BK=32, 4 waves (2x2), fragments 4x4 of 16x16.
// EPI 0: rope(tab) -> out0 bf16 (q projection, rows chunk-local)
// EPI 1: rope(tab); c<512 -> out0 (k, [row][512]); c>=512 -> out1 (vT [b,h][d][pos])
// EPI 2: out0 = acc + bias + res (bf16 residual add)
template <int EPI>
__global__ __launch_bounds__(256) void k_mgemm(
    const u16* __restrict__ A, const u16* __restrict__ W,
    const int N, const int K,
    u16* __restrict__ out0, u16* __restrict__ out1,
    const float* __restrict__ bias, const u16* __restrict__ res,
    const float* __restrict__ tab)
{
    __shared__ u16 Al[128 * 32];
    __shared__ u16 Bl[128 * 32];
    const int bm = blockIdx.y << 7, bn = blockIdx.x << 7;
    const int tid = threadIdx.x;
    const int w = tid >> 6, l = tid & 63;
    const int wm = w >> 1, wn = w & 1;
    const int srow = tid >> 2, skq = (tid & 3) << 3;
    const int lr = l & 15, hi = l >> 4;
    const u16* Ap = A + (size_t)(bm + srow) * K + skq;
    const u16* Wp = W + (size_t)(bn + srow) * K + skq;
    f32x4 acc[4][4];
#pragma unroll
    for (int i = 0; i < 4; i++)
#pragma unroll
        for (int j = 0; j < 4; j++)
#pragma unroll
            for (int e = 0; e < 4; e++) acc[i][j][e] = 0.f;
    for (int k0 = 0; k0 < K; k0 += 32) {
        const uint4 a0 = *(const uint4*)(Ap + k0);
        const uint4 a1 = *(const uint4*)(Ap + (size_t)64 * K + k0);
        const uint4 b0 = *(const uint4*)(Wp + k0);
        const uint4 b1 = *(const uint4*)(Wp + (size_t)64 * K + k0);
        __syncthreads();
        *(uint4*)&Al[srow * 32 + skq] = a0;
        *(uint4*)&Al[(srow + 64) * 32 + skq] = a1;
        *(uint4*)&Bl[srow * 32 + skq] = b0;
        *(uint4*)&Bl[(srow + 64) * 32 + skq] = b1;
        __syncthreads();
        bf16x8 av[4], bv[4];
#pragma unroll
        for (int mi = 0; mi < 4; mi++)
            av[mi] = *(const bf16x8*)&Al[(wm * 64 + mi * 16 + lr) * 32 + hi * 8];
#pragma unroll
        for (int nj = 0; nj < 4; nj++)
            bv[nj] = *(const bf16x8*)&Bl[(wn * 64 + nj * 16 + lr) * 32 + hi * 8];
#pragma unroll
        for (int mi = 0; mi < 4; mi++)
#pragma unroll
            for (int nj = 0; nj < 4; nj++)
                acc[mi][nj] = mfma32(av[mi], bv[nj], acc[mi][nj]);
    }
#pragma unroll
    for (int mi = 0; mi < 4; mi++) {
#pragma unroll
        for (int nj = 0; nj < 4; nj++) {
            const int c = bn + wn * 64 + nj * 16 + lr;
#pragma unroll
            for (int j = 0; j < 4; j++) {
                const int r = bm + wm * 64 + mi * 16 + hi * 4 + j;
                const float x = acc[mi][nj][j];
                if (EPI == 2) {
                    const float y = x + bias[c] + b2f(res[(size_t)r * 512 + c]);
                    out0[(size_t)r * 512 + c] = f2b(y);
                } else {
                    const float p = __shfl_xor(x, 1);
                    const int ci = c & 63;
                    float y = x;
                    if (ci < 32) {
                        const int ii = ci >> 1;
                        const float cc = tab[((size_t)r << 5) + (ii << 1)];
                        const float ss = tab[((size_t)r << 5) + (ii << 1) + 1];
                        y = (c & 1) ? fmaf(x, cc, p * ss) : fmaf(x, cc, -p * ss);
                    }
                    if (EPI == 0) {
                        out0[(size_t)r * 512 + c] = f2b(y);
                    } else {
                        if (c < 512) {
                            out0[(size_t)r * 512 + c] = f2b(y);
                        } else {
                            const int d = c - 512, hh = d >> 6, dd = d & 63;
                            const int bq = r >> 10, pos = r & 1023;
                            out1[(((size_t)(bq * 8 + hh)) * 64 + dd) * 1024 + pos] = f2b(y);
                        }
                    }
                }
            }
        }
    }
}

// ---------------- FFN1: dual MFMA GEMM + exact gelu gate --------------------
// block: 128 rows x 64 paired-cols (a-col c and g-col c+2048). B-tile rows
// 0..63 = W1[bn..], 64..127 = W1[2048+bn..]. wave (wm,wn): 64 rows x 32 cols.
__global__ __launch_bounds__(256) void k_mffn1(
    const u16* __restrict__ A, const u16* __restrict__ W1,
    const float* __restrict__ b1, u16* __restrict__ ag)
{
    __shared__ u16 Al[128 * 32];
    __shared__ u16 Bl[128 * 32];
    const int bm = blockIdx.y << 7, bn = blockIdx.x << 6;
    const int tid = threadIdx.x;
    const int w = tid >> 6, l = tid & 63;
    const int wm = w >> 1, wn = w & 1;
    const int srow = tid >> 2, skq = (tid & 3) << 3;
    const int lr = l & 15, hi = l >> 4;
    const u16* Ap  = A  + (size_t)(bm + srow) * 512 + skq;
    const u16* Wap = W1 + (size_t)(bn + srow) * 512 + skq;
    const u16* Wgp = W1 + (size_t)(2048 + bn + srow) * 512 + skq;
    f32x4 acca[4][2], accg[4][2];
#pragma unroll
    for (int i = 0; i < 4; i++)
#pragma unroll
        for (int j = 0; j < 2; j++)
#pragma unroll
            for (int e = 0; e < 4; e++) { acca[i][j][e] = 0.f; accg[i][j][e] = 0.f; }
    for (int k0 = 0; k0 < 512; k0 += 32) {
        const uint4 a0 = *(const uint4*)(Ap + k0);
        const uint4 a1 = *(const uint4*)(Ap + (size_t)64 * 512 + k0);
        const uint4 w0 = *(const uint4*)(Wap + k0);
        const uint4 w1v = *(const uint4*)(Wgp + k0);
        __syncthreads();
        *(uint4*)&Al[srow * 32 + skq] = a0;
        *(uint4*)&Al[(srow + 64) * 32 + skq] = a1;
        *(uint4*)&Bl[srow * 32 + skq] = w0;
        *(uint4*)&Bl[(srow + 64) * 32 + skq] = w1v;
        __syncthreads();
        bf16x8 av[4], ba[2], bg[2];
#pragma unroll
        for (int mi = 0; mi < 4; mi++)
            av[mi] = *(const bf16x8*)&Al[(wm * 64 + mi * 16 + lr) * 32 + hi * 8];
#pragma unroll
        for (int nj = 0; nj < 2; nj++) {
            ba[nj] = *(const bf16x8*)&Bl[(wn * 32 + nj * 16 + lr) * 32 + hi * 8];
            bg[nj] = *(const bf16x8*)&Bl[(wn * 32 + nj * 16 + lr + 64) * 32 + hi * 8];
        }
#pragma unroll
        for (int mi = 0; mi < 4; mi++)
#pragma unroll
            for (int nj = 0; nj < 2; nj++) {
                acca[mi][nj] = mfma32(av[mi], ba[nj], acca[mi][nj]);
                accg[mi][nj] = mfma32(av[mi], bg[nj], accg[mi][nj]);
            }
    }
#pragma unroll
    for (int mi = 0; mi < 4; mi++)
#pragma unroll
        for (int nj = 0; nj < 2; nj++) {
            const int c = bn + wn * 32 + nj * 16 + lr;
#pragma unroll
            for (int j = 0; j < 4; j++) {
                const int r = bm + wm * 64 + mi * 16 + hi * 4 + j;
                const float a = acca[mi][nj][j] + b1[c];
                const float g = accg[mi][nj][j] + b1[2048 + c];
                const float ge = 0.5f * g * (1.f + erff(g * 0.70710678118654752f));
                ag[(size_t)r * 2048 + c] = f2b(a * ge);
            }
        }
}

// ---------------- attention: MFMA, LDS-free, barrier-free -------------------
// grid (CQ/64, 8), 256 thr = 4 waves, wave = 16 q rows. 64-key chunks.
// S^T = mfma(K, Q): lane owns q=l&15, keys 16t+4hi+j -> softmax = 2 shfl_xor.
// P^T stays in regs and is exactly the B-fragment of 16x16x16 PV mfma.
__global__ __launch_bounds__(256) void k_mattn(
    const u16* __restrict__ q, const u16* __restrict__ kbuf,
    const u16* __restrict__ vT, const float* __restrict__ tab,
    u16* __restrict__ ao, const int b)
{
    const int h = blockIdx.y, tid = threadIdx.x;
    const int w = tid >> 6, l = tid & 63;
    const int lr = l & 15, hi = l >> 4;
    const int qr = blockIdx.x * 64 + w * 16 + lr;   // chunk-local q row
    const bf16x8 qf0 = *(const bf16x8*)&q[(size_t)qr * 512 + h * 64 + hi * 8];
    const bf16x8 qf1 = *(const bf16x8*)&q[(size_t)qr * 512 + h * 64 + hi * 8 + 32];
    const u16* Kp = kbuf + (size_t)b * 524288 + h * 64;
    const u16* Vp = vT + ((size_t)(b * 8 + h)) * 65536;
    f32x4 accO[4];
#pragma unroll
    for (int dj = 0; dj < 4; dj++)
#pragma unroll
        for (int e = 0; e < 4; e++) accO[dj][e] = 0.f;
    float mrun = -1e30f, lrun = 0.f;
    for (int kc = 0; kc < 1024; kc += 64) {
        f32x4 st[4];
#pragma unroll
        for (int t = 0; t < 4; t++) {
#pragma unroll
            for (int e = 0; e < 4; e++) st[t][e] = 0.f;
            const size_t krow = (size_t)(kc + t * 16 + lr) * 512 + hi * 8;
            const bf16x8 kf0 = *(const bf16x8*)&Kp[krow];
            const bf16x8 kf1 = *(const bf16x8*)&Kp[krow + 32];
            st[t] = mfma32(kf0, qf0, st[t]);
            st[t] = mfma32(kf1, qf1, st[t]);
        }
        float mx = -1e30f;
#pragma unroll
        for (int t = 0; t < 4; t++)
#pragma unroll
            for (int j = 0; j < 4; j++) { st[t][j] *= 0.125f; mx = fmaxf(mx, st[t][j]); }
        mx = fmaxf(mx, __shfl_xor(mx, 16));
        mx = fmaxf(mx, __shfl_xor(mx, 32));
        const float mnew = fmaxf(mrun, mx);
        const float alpha = expf(mrun - mnew);
        float ps = 0.f;
        bf16x4 pT[4];
#pragma unroll
        for (int t = 0; t < 4; t++)
#pragma unroll
            for (int j = 0; j < 4; j++) {
                const float p = expf(st[t][j] - mnew);
                ps += p;
                pT[t][j] = (short)f2b(p);
            }
        ps += __shfl_xor(ps, 16);
        ps += __shfl_xor(ps, 32);
        lrun = lrun * alpha + ps;
        mrun = mnew;
#pragma unroll
        for (int dj = 0; dj < 4; dj++)
#pragma unroll
            for (int e = 0; e < 4; e++) accO[dj][e] *= alpha;
#pragma unroll
        for (int dj = 0; dj < 4; dj++)
#pragma unroll
            for (int t = 0; t < 4; t++) {
                const bf16x4 vf = *(const bf16x4*)&Vp[(size_t)(dj * 16 + lr) * 1024 + kc + t * 16 + hi * 4];
                accO[dj] = mfma16(vf, pT[t], accO[dj]);
            }
    }
    const float invl = 1.f / lrun;
#pragma unroll
    for (int dj = 0; dj < 4; dj++) {
        const int d0 = dj * 16 + hi * 4;
        float y[4];
#pragma unroll
        for (int pp = 0; pp < 2; pp++) {
            const float x0 = accO[dj][2 * pp] * invl;
            const float x1 = accO[dj][2 * pp + 1] * invl;
            const int ii = (d0 >> 1) + pp;
            if (ii < 16) {
                const float cc = tab[((size_t)qr << 5) + (ii << 1)];
                const float ss = tab[((size_t)qr << 5) + (ii << 1) + 1];
                y[2 * pp]     = fmaf(x0, cc, x1 * ss);    // inverse rotation
                y[2 * pp + 1] = fmaf(x1, cc, -x0 * ss);
            } else {
                y[2 * pp] = x0; y[2 * pp + 1] = x1;
            }
        }
        ushort4 o;
        o.x = f2b(y[0]); o.y = f2b(y[1]); o.z = f2b(y[2]); o.w = f2b(y[3]);
        *(ushort4*)&ao[(size_t)qr * 512 + h * 64 + d0] = o;
    }
}

// ---------------- final: LN + dot with wproj (bf16 in, f32 out) -------------
__global__ __launch_bounds__(128) void k_final(
    const u16* __restrict__ dec, const float* __restrict__ w,
    const float* __restrict__ bb, const float* __restrict__ wproj,
    const float* __restrict__ bproj, float* __restrict__ out)
{
    const int r = blockIdx.x, tid = threadIdx.x, c0 = tid << 2;
    const ushort4 xi = *(const ushort4*)&dec[(size_t)r * 512 + c0];
    float4 x;
    x.x = b2f(xi.x); x.y = b2f(xi.y); x.z = b2f(xi.z); x.w = b2f(xi.w);
    float s  = x.x + x.y + x.z + x.w;
    float s2 = x.x * x.x + x.y * x.y + x.z * x.z + x.w * x.w;
#pragma unroll
    for (int o = 32; o > 0; o >>= 1) { s += __shfl_down(s, o); s2 += __shfl_down(s2, o); }
    __shared__ float buf[4];
    if ((tid & 63) == 0) { buf[(tid >> 6) << 1] = s; buf[((tid >> 6) << 1) + 1] = s2; }
    __syncthreads();
    s = buf[0] + buf[2]; s2 = buf[1] + buf[3];
    const float mu = s * (1.f / 512.f);
    const float rs = rsqrtf(s2 * (1.f / 512.f) - mu * mu + 1e-5f);
    const float4 w4 = *(const float4*)&w[c0];
    const float4 b4 = *(const float4*)&bb[c0];
    const float4 p4 = *(const float4*)&wproj[c0];
    float part = ((x.x - mu) * rs * w4.x + b4.x) * p4.x
               + ((x.y - mu) * rs * w4.y + b4.y) * p4.y
               + ((x.z - mu) * rs * w4.z + b4.z) * p4.z
               + ((x.w - mu) * rs * w4.w + b4.w) * p4.w;
#pragma unroll
    for (int o = 32; o > 0; o >>= 1) part += __shfl_down(part, o);
    __shared__ float buf2[2];
    if ((tid & 63) == 0) buf2[tid >> 6] = part;
    __syncthreads();
    if (tid == 0) out[r] = buf2[0] + buf2[1] + bproj[0];
}

// ---------------------------------------------------------------------------
extern "C" void kernel_launch(void* const* d_in, const int* in_sizes, int n_in,
                              void* d_out, int out_size, void* d_ws, size_t ws_size,
                              hipStream_t stream)
{
    (void)in_sizes; (void)n_in; (void)out_size;
    const float* enc  = (const float*)d_in[0];
    const float* lts  = (const float*)d_in[1];
    const int*   qidx = (const int*)  d_in[2];
    const float* qts  = (const float*)d_in[3];
    const float* uemb = (const float*)d_in[4];
    const float* vpb  = (const float*)d_in[6];
    const float* canw = (const float*)d_in[7];
    const float* canb = (const float*)d_in[8];
    const float* ccw  = (const float*)d_in[9];
    const float* ccb  = (const float*)d_in[10];
    const float* wq   = (const float*)d_in[11];
    const float* wkv  = (const float*)d_in[12];
    const float* wo   = (const float*)d_in[13];
    const float* bo   = (const float*)d_in[14];
    const float* flnw = (const float*)d_in[15];
    const float* flnb = (const float*)d_in[16];
    const float* w1   = (const float*)d_in[17];
    const float* b1   = (const float*)d_in[18];
    const float* w2   = (const float*)d_in[19];
    const float* b2   = (const float*)d_in[20];
    const float* olnw = (const float*)d_in[21];
    const float* olnb = (const float*)d_in[22];
    const float* wpj  = (const float*)d_in[23];
    const float* bpj  = (const float*)d_in[24];
    float* outp = (float*)d_out;

    // workspace: f32 tabs, then bf16 region
    float* tabq = (float*)d_ws;              // 16384*32
    float* tabl = tabq + 524288;             // 4096*32
    u16* wqb  = (u16*)(tabl + 131072);       // 512*512
    u16* wkvb = wqb + 262144;                // 1024*512
    u16* wob  = wkvb + 524288;               // 512*512
    u16* w1b  = wob + 262144;                // 4096*512
    u16* w2b  = w1b + 2097152;               // 512*2048
    u16* cn   = w2b + 1048576;               // 4096*512
    u16* kb   = cn + 2097152;                // 4096*512
    u16* vT   = kb + 2097152;                // 4*8*64*1024
    const size_t shared_b = 2621440 + (size_t)(4194304 + 3 * 2097152) * 2;
    int CQ = 4096;
    while (CQ > 512 && shared_b + (size_t)CQ * 9216 > ws_size) CQ >>= 1;
    u16* qtokC = vT + 2097152;               // CQ*512
    u16* xnC   = qtokC + (size_t)CQ * 512;   // CQ*512 (reused: ln_dec)
    u16* qC    = xnC + (size_t)CQ * 512;     // CQ*512 (reused: dec_final)
    u16* aoC   = qC + (size_t)CQ * 512;      // CQ*512
    u16* d2C   = aoC + (size_t)CQ * 512;     // CQ*512
    u16* agC   = d2C + (size_t)CQ * 512;     // CQ*2048

    k_cvt<<<256, 256, 0, stream>>>(wq, wqb, 262144);
    k_cvt<<<512, 256, 0, stream>>>(wkv, wkvb, 524288);
    k_cvt<<<256, 256, 0, stream>>>(wo, wob, 262144);
    k_cvt<<<2048, 256, 0, stream>>>(w1, w1b, 2097152);
    k_cvt<<<1024, 256, 0, stream>>>(w2, w2b, 1048576);
    k_rope_tab16<<<1024, 256, 0, stream>>>(qts, tabq, 16384);
    k_rope_tab16<<<256, 256, 0, stream>>>(lts, tabl, 4096);
    k_ln_f<<<4096, 128, 0, stream>>>(enc, ccw, ccb, cn);
    k_mgemm<1><<<dim3(8, 32), 256, 0, stream>>>(cn, wkvb, 1024, 512,
                                                kb, vT, nullptr, nullptr, tabl);

    for (int b = 0; b < 4; ++b) {
        for (int g0 = 0; g0 < 4096; g0 += CQ) {
            const int rowbase = b * 4096 + g0;
            const float* tabqc = tabq + (size_t)rowbase * 32;
            k_qtok_ln<<<CQ, 128, 0, stream>>>(qidx + rowbase, uemb, vpb, canw, canb,
                                              qtokC, xnC);
            k_mgemm<0><<<dim3(4, CQ / 128), 256, 0, stream>>>(xnC, wqb, 512, 512,
                                                              qC, nullptr, nullptr, nullptr, tabqc);
            k_mattn<<<dim3(CQ / 64, 8), 256, 0, stream>>>(qC, kb, vT, tabqc, aoC, b);
            k_mgemm<2><<<dim3(4, CQ / 128), 256, 0, stream>>>(aoC, wob, 512, 512,
                                                              d2C, nullptr, bo, qtokC, nullptr);
            k_ln_h<<<CQ, 128, 0, stream>>>(d2C, flnw, flnb, xnC);
            k_mffn1<<<dim3(32, CQ / 128), 256, 0, stream>>>(xnC, w1b, b1, agC);
            k_mgemm<2><<<dim3(4, CQ / 128), 256, 0, stream>>>(agC, w2b, 512, 2048,
                                                              qC, nullptr, b2, d2C, nullptr);
            k_final<<<CQ, 128, 0, stream>>>(qC, olnw, olnb, wpj, bpj, outp + rowbase);
        }
    }
}

// Round 5
// 623.353 us; speedup vs baseline: 4.8032x; 1.4505x over previous
//
#include <hip/hip_runtime.h>
#include <math.h>

// ---------------------------------------------------------------------------
// MaskingDecoder bf16-MFMA v3: r3-proven kernels + unified pipeline chunk.
// B=4, NQ=4096, NL=1024, DIM=512, HEADS=8, DH=64, hid=2048
// GEMMs: 128x128 tile, register-staged LDS, 16x16x32_bf16, fp32 accum.
// Attention: LDS-free, swapped QK^T, in-register P^T, 16x16x16 PV.
// ---------------------------------------------------------------------------

typedef unsigned short u16;
typedef __attribute__((ext_vector_type(8))) short bf16x8;
typedef __attribute__((ext_vector_type(4))) short bf16x4;
typedef __attribute__((ext_vector_type(4))) float f32x4;

__device__ __forceinline__ u16 f2b(float x) {
    union { float f; unsigned u; } v; v.f = x;
    unsigned r = v.u + 0x7fffu + ((v.u >> 16) & 1u);
    return (u16)(r >> 16);
}
__device__ __forceinline__ float b2f(u16 h) {
    union { unsigned u; float f; } v; v.u = ((unsigned)h) << 16;
    return v.f;
}
__device__ __forceinline__ f32x4 mfma32(bf16x8 a, bf16x8 b, f32x4 c) {
    return __builtin_amdgcn_mfma_f32_16x16x32_bf16(a, b, c, 0, 0, 0);
}
__device__ __forceinline__ f32x4 mfma16(bf16x4 a, bf16x4 b, f32x4 c) {
    asm("v_mfma_f32_16x16x16_bf16 %0, %1, %2, %0" : "+v"(c) : "v"(a), "v"(b));
    return c;
}

// ---------------- f32 -> bf16 weight convert --------------------------------
__global__ __launch_bounds__(256) void k_cvt(const float* __restrict__ in,
                                             u16* __restrict__ out, const int n)
{
    const int i = (blockIdx.x * 256 + threadIdx.x) * 4;
    if (i >= n) return;
    const float4 v = *(const float4*)&in[i];
    ushort4 o;
    o.x = f2b(v.x); o.y = f2b(v.y); o.z = f2b(v.z); o.w = f2b(v.w);
    *(ushort4*)&out[i] = o;
}

// ---------------- rope table: 16 (cos,sin) pairs per row --------------------
__global__ void k_rope_tab16(const float* __restrict__ t, float* __restrict__ tab,
                             const int n)
{
    const int idx = blockIdx.x * 256 + threadIdx.x;
    if (idx >= n * 16) return;
    const int r = idx >> 4, i = idx & 15;
    const float b0 = (float)(1e-4 / 2.0627);
    const float a0 = (float)(2.0 * 3.14159265358979323846 / 1e-4);
    const float invf = a0 * (float)pow((double)b0, (double)i * (1.0 / 16.0));
    const float ang = t[r] * invf;
    float sn, cs;
    sincosf(ang, &sn, &cs);
    tab[((size_t)r << 5) + (i << 1)]     = cs;
    tab[((size_t)r << 5) + (i << 1) + 1] = sn;
}

// ---------------- qtok build + layernorm -> bf16 ----------------------------
__global__ __launch_bounds__(128) void k_qtok_ln(
    const int* __restrict__ qidx, const float* __restrict__ uemb,
    const float* __restrict__ vpb, const float* __restrict__ w,
    const float* __restrict__ bb, u16* __restrict__ qtok, u16* __restrict__ xn)
{
    const int r = blockIdx.x, tid = threadIdx.x, c0 = tid << 2;
    float4 x;
    if (c0 < 256) {
        x = *(const float4*)&vpb[c0];
    } else {
        const int u = qidx[r];
        x = *(const float4*)&uemb[(size_t)u * 256 + (c0 - 256)];
    }
    ushort4 qo;
    qo.x = f2b(x.x); qo.y = f2b(x.y); qo.z = f2b(x.z); qo.w = f2b(x.w);
    *(ushort4*)&qtok[(size_t)r * 512 + c0] = qo;
    float s  = x.x + x.y + x.z + x.w;
    float s2 = x.x * x.x + x.y * x.y + x.z * x.z + x.w * x.w;
#pragma unroll
    for (int o = 32; o > 0; o >>= 1) { s += __shfl_down(s, o); s2 += __shfl_down(s2, o); }
    __shared__ float buf[4];
    if ((tid & 63) == 0) { buf[(tid >> 6) << 1] = s; buf[((tid >> 6) << 1) + 1] = s2; }
    __syncthreads();
    s = buf[0] + buf[2]; s2 = buf[1] + buf[3];
    const float mu = s * (1.f / 512.f);
    const float rs = rsqrtf(s2 * (1.f / 512.f) - mu * mu + 1e-5f);
    const float4 w4 = *(const float4*)&w[c0];
    const float4 b4 = *(const float4*)&bb[c0];
    ushort4 yo;
    yo.x = f2b((x.x - mu) * rs * w4.x + b4.x);
    yo.y = f2b((x.y - mu) * rs * w4.y + b4.y);
    yo.z = f2b((x.z - mu) * rs * w4.z + b4.z);
    yo.w = f2b((x.w - mu) * rs * w4.w + b4.w);
    *(ushort4*)&xn[(size_t)r * 512 + c0] = yo;
}

// ---------------- layernorm f32-in -> bf16-out ------------------------------
__global__ __launch_bounds__(128) void k_ln_f(
    const float* __restrict__ in, const float* __restrict__ w,
    const float* __restrict__ bb, u16* __restrict__ outp)
{
    const int r = blockIdx.x, tid = threadIdx.x, c0 = tid << 2;
    const float4 x = *(const float4*)&in[(size_t)r * 512 + c0];
    float s  = x.x + x.y + x.z + x.w;
    float s2 = x.x * x.x + x.y * x.y + x.z * x.z + x.w * x.w;
#pragma unroll
    for (int o = 32; o > 0; o >>= 1) { s += __shfl_down(s, o); s2 += __shfl_down(s2, o); }
    __shared__ float buf[4];
    if ((tid & 63) == 0) { buf[(tid >> 6) << 1] = s; buf[((tid >> 6) << 1) + 1] = s2; }
    __syncthreads();
    s = buf[0] + buf[2]; s2 = buf[1] + buf[3];
    const float mu = s * (1.f / 512.f);
    const float rs = rsqrtf(s2 * (1.f / 512.f) - mu * mu + 1e-5f);
    const float4 w4 = *(const float4*)&w[c0];
    const float4 b4 = *(const float4*)&bb[c0];
    ushort4 yo;
    yo.x = f2b((x.x - mu) * rs * w4.x + b4.x);
    yo.y = f2b((x.y - mu) * rs * w4.y + b4.y);
    yo.z = f2b((x.z - mu) * rs * w4.z + b4.z);
    yo.w = f2b((x.w - mu) * rs * w4.w + b4.w);
    *(ushort4*)&outp[(size_t)r * 512 + c0] = yo;
}

// ---------------- layernorm bf16-in -> bf16-out -----------------------------
__global__ __launch_bounds__(128) void k_ln_h(
    const u16* __restrict__ in, const float* __restrict__ w,
    const float* __restrict__ bb, u16* __restrict__ outp)
{
    const int r = blockIdx.x, tid = threadIdx.x, c0 = tid << 2;
    const ushort4 xi = *(const ushort4*)&in[(size_t)r * 512 + c0];
    float4 x;
    x.x = b2f(xi.x); x.y = b2f(xi.y); x.z = b2f(xi.z); x.w = b2f(xi.w);
    float s  = x.x + x.y + x.z + x.w;
    float s2 = x.x * x.x + x.y * x.y + x.z * x.z + x.w * x.w;
#pragma unroll
    for (int o = 32; o > 0; o >>= 1) { s += __shfl_down(s, o); s2 += __shfl_down(s2, o); }
    __shared__ float buf[4];
    if ((tid & 63) == 0) { buf[(tid >> 6) << 1] = s; buf[((tid >> 6) << 1) + 1] = s2; }
    __syncthreads();
    s = buf[0] + buf[2]; s2 = buf[1] + buf[3];
    const float mu = s * (1.f / 512.f);
    const float rs = rsqrtf(s2 * (1.f / 512.f) - mu * mu + 1e-5f);
    const float4 w4 = *(const float4*)&w[c0];
    const float4 b4 = *(const float4*)&bb[c0];
    ushort4 yo;
    yo.x = f2b((x.x - mu) * rs * w4.x + b4.x);
    yo.y = f2b((x.y - mu) * rs * w4.y + b4.y);
    yo.z = f2b((x.z - mu) * rs * w4.z + b4.z);
    yo.w = f2b((x.w - mu) * rs * w4.w + b4.w);
    *(ushort4*)&outp[(size_t)r * 512 + c0] = yo;
}

// ---------------- MFMA GEMM: C[m,n] = sum_k A[m,k]*W[n,k] -------------------
// 128x128 tile, BK=32, 4 waves (2x2), register-staged LDS (r3-proven).
// EPI 0: rope(tab) -> out0 bf16
// EPI 1: rope(tab); c<512 -> out0 (k); c>=512 -> out1 (vT [b,h][d][pos])
// EPI 2: out0 = acc + bias + res (bf16 residual add)
template <int EPI>
__global__ __launch_bounds__(256) void k_mgemm(
    const u16* __restrict__ A, const u16* __restrict__ W,
    const int N, const int K,
    u16* __restrict__ out0, u16* __restrict__ out1,
    const float* __restrict__ bias, const u16* __restrict__ res,
    const float* __restrict__ tab)
{
    __shared__ u16 Al[128 * 32];
    __shared__ u16 Bl[128 * 32];
    const int bm = blockIdx.y << 7, bn = blockIdx.x << 7;
    const int tid = threadIdx.x;
    const int w = tid >> 6, l = tid & 63;
    const int wm = w >> 1, wn = w & 1;
    const int srow = tid >> 2, skq = (tid & 3) << 3;
    const int lr = l & 15, hi = l >> 4;
    const u16* Ap = A + (size_t)(bm + srow) * K + skq;
    const u16* Wp = W + (size_t)(bn + srow) * K + skq;
    f32x4 acc[4][4];
#pragma unroll
    for (int i = 0; i < 4; i++)
#pragma unroll
        for (int j = 0; j < 4; j++)
#pragma unroll
            for (int e = 0; e < 4; e++) acc[i][j][e] = 0.f;
    for (int k0 = 0; k0 < K; k0 += 32) {
        const uint4 a0 = *(const uint4*)(Ap + k0);
        const uint4 a1 = *(const uint4*)(Ap + (size_t)64 * K + k0);
        const uint4 b0 = *(const uint4*)(Wp + k0);
        const uint4 b1 = *(const uint4*)(Wp + (size_t)64 * K + k0);
        __syncthreads();
        *(uint4*)&Al[srow * 32 + skq] = a0;
        *(uint4*)&Al[(srow + 64) * 32 + skq] = a1;
        *(uint4*)&Bl[srow * 32 + skq] = b0;
        *(uint4*)&Bl[(srow + 64) * 32 + skq] = b1;
        __syncthreads();
        bf16x8 av[4], bv[4];
#pragma unroll
        for (int mi = 0; mi < 4; mi++)
            av[mi] = *(const bf16x8*)&Al[(wm * 64 + mi * 16 + lr) * 32 + hi * 8];
#pragma unroll
        for (int nj = 0; nj < 4; nj++)
            bv[nj] = *(const bf16x8*)&Bl[(wn * 64 + nj * 16 + lr) * 32 + hi * 8];
#pragma unroll
        for (int mi = 0; mi < 4; mi++)
#pragma unroll
            for (int nj = 0; nj < 4; nj++)
                acc[mi][nj] = mfma32(av[mi], bv[nj], acc[mi][nj]);
    }
#pragma unroll
    for (int mi = 0; mi < 4; mi++) {
#pragma unroll
        for (int nj = 0; nj < 4; nj++) {
            const int c = bn + wn * 64 + nj * 16 + lr;
#pragma unroll
            for (int j = 0; j < 4; j++) {
                const int r = bm + wm * 64 + mi * 16 + hi * 4 + j;
                const float x = acc[mi][nj][j];
                if (EPI == 2) {
                    const float y = x + bias[c] + b2f(res[(size_t)r * 512 + c]);
                    out0[(size_t)r * 512 + c] = f2b(y);
                } else {
                    const float p = __shfl_xor(x, 1);
                    const int ci = c & 63;
                    float y = x;
                    if (ci < 32) {
                        const int ii = ci >> 1;
                        const float cc = tab[((size_t)r << 5) + (ii << 1)];
                        const float ss = tab[((size_t)r << 5) + (ii << 1) + 1];
                        y = (c & 1) ? fmaf(x, cc, p * ss) : fmaf(x, cc, -p * ss);
                    }
                    if (EPI == 0) {
                        out0[(size_t)r * 512 + c] = f2b(y);
                    } else {
                        if (c < 512) {
                            out0[(size_t)r * 512 + c] = f2b(y);
                        } else {
                            const int d = c - 512, hh = d >> 6, dd = d & 63;
                            const int bq = r >> 10, pos = r & 1023;
                            out1[(((size_t)(bq * 8 + hh)) * 64 + dd) * 1024 + pos] = f2b(y);
                        }
                    }
                }
            }
        }
    }
}

// ---------------- FFN1: dual MFMA GEMM + exact gelu gate --------------------
__global__ __launch_bounds__(256) void k_mffn1(
    const u16* __restrict__ A, const u16* __restrict__ W1,
    const float* __restrict__ b1, u16* __restrict__ ag)
{
    __shared__ u16 Al[128 * 32];
    __shared__ u16 Bl[128 * 32];
    const int bm = blockIdx.y << 7, bn = blockIdx.x << 6;
    const int tid = threadIdx.x;
    const int w = tid >> 6, l = tid & 63;
    const int wm = w >> 1, wn = w & 1;
    const int srow = tid >> 2, skq = (tid & 3) << 3;
    const int lr = l & 15, hi = l >> 4;
    const u16* Ap  = A  + (size_t)(bm + srow) * 512 + skq;
    const u16* Wap = W1 + (size_t)(bn + srow) * 512 + skq;
    const u16* Wgp = W1 + (size_t)(2048 + bn + srow) * 512 + skq;
    f32x4 acca[4][2], accg[4][2];
#pragma unroll
    for (int i = 0; i < 4; i++)
#pragma unroll
        for (int j = 0; j < 2; j++)
#pragma unroll
            for (int e = 0; e < 4; e++) { acca[i][j][e] = 0.f; accg[i][j][e] = 0.f; }
    for (int k0 = 0; k0 < 512; k0 += 32) {
        const uint4 a0 = *(const uint4*)(Ap + k0);
        const uint4 a1 = *(const uint4*)(Ap + (size_t)64 * 512 + k0);
        const uint4 w0 = *(const uint4*)(Wap + k0);
        const uint4 w1v = *(const uint4*)(Wgp + k0);
        __syncthreads();
        *(uint4*)&Al[srow * 32 + skq] = a0;
        *(uint4*)&Al[(srow + 64) * 32 + skq] = a1;
        *(uint4*)&Bl[srow * 32 + skq] = w0;
        *(uint4*)&Bl[(srow + 64) * 32 + skq] = w1v;
        __syncthreads();
        bf16x8 av[4], ba[2], bg[2];
#pragma unroll
        for (int mi = 0; mi < 4; mi++)
            av[mi] = *(const bf16x8*)&Al[(wm * 64 + mi * 16 + lr) * 32 + hi * 8];
#pragma unroll
        for (int nj = 0; nj < 2; nj++) {
            ba[nj] = *(const bf16x8*)&Bl[(wn * 32 + nj * 16 + lr) * 32 + hi * 8];
            bg[nj] = *(const bf16x8*)&Bl[(wn * 32 + nj * 16 + lr + 64) * 32 + hi * 8];
        }
#pragma unroll
        for (int mi = 0; mi < 4; mi++)
#pragma unroll
            for (int nj = 0; nj < 2; nj++) {
                acca[mi][nj] = mfma32(av[mi], ba[nj], acca[mi][nj]);
                accg[mi][nj] = mfma32(av[mi], bg[nj], accg[mi][nj]);
            }
    }
#pragma unroll
    for (int mi = 0; mi < 4; mi++)
#pragma unroll
        for (int nj = 0; nj < 2; nj++) {
            const int c = bn + wn * 32 + nj * 16 + lr;
#pragma unroll
            for (int j = 0; j < 4; j++) {
                const int r = bm + wm * 64 + mi * 16 + hi * 4 + j;
                const float a = acca[mi][nj][j] + b1[c];
                const float g = accg[mi][nj][j] + b1[2048 + c];
                const float ge = 0.5f * g * (1.f + erff(g * 0.70710678118654752f));
                ag[(size_t)r * 2048 + c] = f2b(a * ge);
            }
        }
}

// ---------------- attention: MFMA, LDS-free, barrier-free (r3-proven) -------
// grid (CQ/64, 8), 256 thr = 4 waves, wave = 16 q rows. 64-key chunks.
// S^T = mfma(K, Q): lane owns q=l&15, keys 16t+4hi+j -> softmax = 2 shfl_xor.
// P^T stays in regs and is exactly the B-fragment of 16x16x16 PV mfma.
__global__ __launch_bounds__(256) void k_mattn(
    const u16* __restrict__ q, const u16* __restrict__ kbuf,
    const u16* __restrict__ vT, const float* __restrict__ tab,
    u16* __restrict__ ao, const int rowbase)
{
    const int h = blockIdx.y, tid = threadIdx.x;
    const int w = tid >> 6, l = tid & 63;
    const int lr = l & 15, hi = l >> 4;
    const int qr = blockIdx.x * 64 + w * 16 + lr;       // chunk-local q row
    const int b = (rowbase + blockIdx.x * 64) >> 12;    // batch
    const bf16x8 qf0 = *(const bf16x8*)&q[(size_t)qr * 512 + h * 64 + hi * 8];
    const bf16x8 qf1 = *(const bf16x8*)&q[(size_t)qr * 512 + h * 64 + hi * 8 + 32];
    const u16* Kp = kbuf + (size_t)b * 524288 + h * 64;
    const u16* Vp = vT + ((size_t)(b * 8 + h)) * 65536;
    f32x4 accO[4];
#pragma unroll
    for (int dj = 0; dj < 4; dj++)
#pragma unroll
        for (int e = 0; e < 4; e++) accO[dj][e] = 0.f;
    float mrun = -1e30f, lrun = 0.f;
    for (int kc = 0; kc < 1024; kc += 64) {
        f32x4 st[4];
#pragma unroll
        for (int t = 0; t < 4; t++) {
#pragma unroll
            for (int e = 0; e < 4; e++) st[t][e] = 0.f;
            const size_t krow = (size_t)(kc + t * 16 + lr) * 512 + hi * 8;
            const bf16x8 kf0 = *(const bf16x8*)&Kp[krow];
            const bf16x8 kf1 = *(const bf16x8*)&Kp[krow + 32];
            st[t] = mfma32(kf0, qf0, st[t]);
            st[t] = mfma32(kf1, qf1, st[t]);
        }
        float mx = -1e30f;
#pragma unroll
        for (int t = 0; t < 4; t++)
#pragma unroll
            for (int j = 0; j < 4; j++) { st[t][j] *= 0.125f; mx = fmaxf(mx, st[t][j]); }
        mx = fmaxf(mx, __shfl_xor(mx, 16));
        mx = fmaxf(mx, __shfl_xor(mx, 32));
        const float mnew = fmaxf(mrun, mx);
        const float alpha = expf(mrun - mnew);
        float ps = 0.f;
        bf16x4 pT[4];
#pragma unroll
        for (int t = 0; t < 4; t++)
#pragma unroll
            for (int j = 0; j < 4; j++) {
                const float p = expf(st[t][j] - mnew);
                ps += p;
                pT[t][j] = (short)f2b(p);
            }
        ps += __shfl_xor(ps, 16);
        ps += __shfl_xor(ps, 32);
        lrun = lrun * alpha + ps;
        mrun = mnew;
#pragma unroll
        for (int dj = 0; dj < 4; dj++)
#pragma unroll
            for (int e = 0; e < 4; e++) accO[dj][e] *= alpha;
#pragma unroll
        for (int dj = 0; dj < 4; dj++)
#pragma unroll
            for (int t = 0; t < 4; t++) {
                const bf16x4 vf = *(const bf16x4*)&Vp[(size_t)(dj * 16 + lr) * 1024 + kc + t * 16 + hi * 4];
                accO[dj] = mfma16(vf, pT[t], accO[dj]);
            }
    }
    const float invl = 1.f / lrun;
#pragma unroll
    for (int dj = 0; dj < 4; dj++) {
        const int d0 = dj * 16 + hi * 4;
        float y[4];
#pragma unroll
        for (int pp = 0; pp < 2; pp++) {
            const float x0 = accO[dj][2 * pp] * invl;
            const float x1 = accO[dj][2 * pp + 1] * invl;
            const int ii = (d0 >> 1) + pp;
            if (ii < 16) {
                const float cc = tab[((size_t)qr << 5) + (ii << 1)];
                const float ss = tab[((size_t)qr << 5) + (ii << 1) + 1];
                y[2 * pp]     = fmaf(x0, cc, x1 * ss);    // inverse rotation
                y[2 * pp + 1] = fmaf(x1, cc, -x0 * ss);
            } else {
                y[2 * pp] = x0; y[2 * pp + 1] = x1;
            }
        }
        ushort4 o;
        o.x = f2b(y[0]); o.y = f2b(y[1]); o.z = f2b(y[2]); o.w = f2b(y[3]);
        *(ushort4*)&ao[(size_t)qr * 512 + h * 64 + d0] = o;
    }
}

// ---------------- final: LN + dot with wproj (bf16 in, f32 out) -------------
__global__ __launch_bounds__(128) void k_final(
    const u16* __restrict__ dec, const float* __restrict__ w,
    const float* __restrict__ bb, const float* __restrict__ wproj,
    const float* __restrict__ bproj, float* __restrict__ out)
{
    const int r = blockIdx.x, tid = threadIdx.x, c0 = tid << 2;
    const ushort4 xi = *(const ushort4*)&dec[(size_t)r * 512 + c0];
    float4 x;
    x.x = b2f(xi.x); x.y = b2f(xi.y); x.z = b2f(xi.z); x.w = b2f(xi.w);
    float s  = x.x + x.y + x.z + x.w;
    float s2 = x.x * x.x + x.y * x.y + x.z * x.z + x.w * x.w;
#pragma unroll
    for (int o = 32; o > 0; o >>= 1) { s += __shfl_down(s, o); s2 += __shfl_down(s2, o); }
    __shared__ float buf[4];
    if ((tid & 63) == 0) { buf[(tid >> 6) << 1] = s; buf[((tid >> 6) << 1) + 1] = s2; }
    __syncthreads();
    s = buf[0] + buf[2]; s2 = buf[1] + buf[3];
    const float mu = s * (1.f / 512.f);
    const float rs = rsqrtf(s2 * (1.f / 512.f) - mu * mu + 1e-5f);
    const float4 w4 = *(const float4*)&w[c0];
    const float4 b4 = *(const float4*)&bb[c0];
    const float4 p4 = *(const float4*)&wproj[c0];
    float part = ((x.x - mu) * rs * w4.x + b4.x) * p4.x
               + ((x.y - mu) * rs * w4.y + b4.y) * p4.y
               + ((x.z - mu) * rs * w4.z + b4.z) * p4.z
               + ((x.w - mu) * rs * w4.w + b4.w) * p4.w;
#pragma unroll
    for (int o = 32; o > 0; o >>= 1) part += __shfl_down(part, o);
    __shared__ float buf2[2];
    if ((tid & 63) == 0) buf2[tid >> 6] = part;
    __syncthreads();
    if (tid == 0) out[r] = buf2[0] + buf2[1] + bproj[0];
}

// ---------------------------------------------------------------------------
extern "C" void kernel_launch(void* const* d_in, const int* in_sizes, int n_in,
                              void* d_out, int out_size, void* d_ws, size_t ws_size,
                              hipStream_t stream)
{
    (void)in_sizes; (void)n_in; (void)out_size;
    const float* enc  = (const float*)d_in[0];
    const float* lts  = (const float*)d_in[1];
    const int*   qidx = (const int*)  d_in[2];
    const float* qts  = (const float*)d_in[3];
    const float* uemb = (const float*)d_in[4];
    const float* vpb  = (const float*)d_in[6];
    const float* canw = (const float*)d_in[7];
    const float* canb = (const float*)d_in[8];
    const float* ccw  = (const float*)d_in[9];
    const float* ccb  = (const float*)d_in[10];
    const float* wq   = (const float*)d_in[11];
    const float* wkv  = (const float*)d_in[12];
    const float* wo   = (const float*)d_in[13];
    const float* bo   = (const float*)d_in[14];
    const float* flnw = (const float*)d_in[15];
    const float* flnb = (const float*)d_in[16];
    const float* w1   = (const float*)d_in[17];
    const float* b1   = (const float*)d_in[18];
    const float* w2   = (const float*)d_in[19];
    const float* b2   = (const float*)d_in[20];
    const float* olnw = (const float*)d_in[21];
    const float* olnb = (const float*)d_in[22];
    const float* wpj  = (const float*)d_in[23];
    const float* bpj  = (const float*)d_in[24];
    float* outp = (float*)d_out;

    // workspace: f32 tabs, then bf16 region
    float* tabq = (float*)d_ws;              // 16384*32
    float* tabl = tabq + 524288;             // 4096*32
    u16* wqb  = (u16*)(tabl + 131072);       // 512*512
    u16* wkvb = wqb + 262144;                // 1024*512
    u16* wob  = wkvb + 524288;               // 512*512
    u16* w1b  = wob + 262144;                // 4096*512
    u16* w2b  = w1b + 2097152;               // 512*2048
    u16* cn   = w2b + 1048576;               // 4096*512
    u16* kb   = cn + 2097152;                // 4096*512
    u16* vT   = kb + 2097152;                // 4*8*64*1024
    const size_t base_b = 2621440ull + 20971520ull;       // tabs + bf16 shared
    int CQ = 16384;
    while (CQ > 512 &&
           base_b + (size_t)CQ * 5120 + (size_t)(CQ < 4096 ? CQ : 4096) * 4096 > ws_size)
        CQ >>= 1;
    int SF = CQ;
    while (SF > 512 && base_b + (size_t)CQ * 5120 + (size_t)SF * 4096 > ws_size)
        SF >>= 1;
    u16* qtokC = vT + 2097152;               // CQ*512
    u16* xnC   = qtokC + (size_t)CQ * 512;   // CQ*512 (reused: ln_dec)
    u16* qC    = xnC + (size_t)CQ * 512;     // CQ*512 (reused: dec_final)
    u16* aoC   = qC + (size_t)CQ * 512;      // CQ*512
    u16* d2C   = aoC + (size_t)CQ * 512;     // CQ*512
    u16* agC   = d2C + (size_t)CQ * 512;     // SF*2048

    k_cvt<<<256, 256, 0, stream>>>(wq, wqb, 262144);
    k_cvt<<<512, 256, 0, stream>>>(wkv, wkvb, 524288);
    k_cvt<<<256, 256, 0, stream>>>(wo, wob, 262144);
    k_cvt<<<2048, 256, 0, stream>>>(w1, w1b, 2097152);
    k_cvt<<<1024, 256, 0, stream>>>(w2, w2b, 1048576);
    k_rope_tab16<<<1024, 256, 0, stream>>>(qts, tabq, 16384);
    k_rope_tab16<<<256, 256, 0, stream>>>(lts, tabl, 4096);
    k_ln_f<<<4096, 128, 0, stream>>>(enc, ccw, ccb, cn);
    k_mgemm<1><<<dim3(8, 32), 256, 0, stream>>>(cn, wkvb, 1024, 512,
                                                kb, vT, nullptr, nullptr, tabl);

    for (int g0 = 0; g0 < 16384; g0 += CQ) {
        const float* tabc = tabq + (size_t)g0 * 32;
        k_qtok_ln<<<CQ, 128, 0, stream>>>(qidx + g0, uemb, vpb, canw, canb,
                                          qtokC, xnC);
        k_mgemm<0><<<dim3(4, CQ / 128), 256, 0, stream>>>(xnC, wqb, 512, 512,
                                                          qC, nullptr, nullptr, nullptr, tabc);
        k_mattn<<<dim3(CQ / 64, 8), 256, 0, stream>>>(qC, kb, vT, tabc, aoC, g0);
        k_mgemm<2><<<dim3(4, CQ / 128), 256, 0, stream>>>(aoC, wob, 512, 512,
                                                          d2C, nullptr, bo, qtokC, nullptr);
        k_ln_h<<<CQ, 128, 0, stream>>>(d2C, flnw, flnb, xnC);
        for (int f0 = 0; f0 < CQ; f0 += SF) {
            k_mffn1<<<dim3(32, SF / 128), 256, 0, stream>>>(xnC + (size_t)f0 * 512,
                                                            w1b, b1, agC);
            k_mgemm<2><<<dim3(4, SF / 128), 256, 0, stream>>>(agC, w2b, 512, 2048,
                                                              qC + (size_t)f0 * 512, nullptr,
                                                              b2, d2C + (size_t)f0 * 512, nullptr);
            k_final<<<SF, 128, 0, stream>>>(qC + (size_t)f0 * 512, olnw, olnb,
                                            wpj, bpj, outp + g0 + f0);
        }
    }
}

// Round 8
// 514.610 us; speedup vs baseline: 5.8182x; 1.2113x over previous
//
#include <hip/hip_runtime.h>
#include <math.h>

// ---------------------------------------------------------------------------
// MaskingDecoder bf16-MFMA v6: r5-passing kernel with PV step rebuilt on the
// builtin 16x16x32 MFMA (no inline asm, no LDS in attention):
//   - V^T read as contiguous bf16x8 per lane (64B-line coalesced)
//   - P^T B-fragment assembled via lane shuffles from softmax registers
// Everything else byte-identical to the 623us r5 kernel.
// ---------------------------------------------------------------------------

typedef unsigned short u16;
typedef __attribute__((ext_vector_type(8))) short bf16x8;
typedef __attribute__((ext_vector_type(4))) float f32x4;

__device__ __forceinline__ u16 f2b(float x) {
    union { float f; unsigned u; } v; v.f = x;
    unsigned r = v.u + 0x7fffu + ((v.u >> 16) & 1u);
    return (u16)(r >> 16);
}
__device__ __forceinline__ float b2f(u16 h) {
    union { unsigned u; float f; } v; v.u = ((unsigned)h) << 16;
    return v.f;
}
__device__ __forceinline__ f32x4 mfma32(bf16x8 a, bf16x8 b, f32x4 c) {
    return __builtin_amdgcn_mfma_f32_16x16x32_bf16(a, b, c, 0, 0, 0);
}

// ---------------- f32 -> bf16 weight convert --------------------------------
__global__ __launch_bounds__(256) void k_cvt(const float* __restrict__ in,
                                             u16* __restrict__ out, const int n)
{
    const int i = (blockIdx.x * 256 + threadIdx.x) * 4;
    if (i >= n) return;
    const float4 v = *(const float4*)&in[i];
    ushort4 o;
    o.x = f2b(v.x); o.y = f2b(v.y); o.z = f2b(v.z); o.w = f2b(v.w);
    *(ushort4*)&out[i] = o;
}

// ---------------- rope table: 16 (cos,sin) pairs per row --------------------
__global__ void k_rope_tab16(const float* __restrict__ t, float* __restrict__ tab,
                             const int n)
{
    const int idx = blockIdx.x * 256 + threadIdx.x;
    if (idx >= n * 16) return;
    const int r = idx >> 4, i = idx & 15;
    const float b0 = (float)(1e-4 / 2.0627);
    const float a0 = (float)(2.0 * 3.14159265358979323846 / 1e-4);
    const float invf = a0 * (float)pow((double)b0, (double)i * (1.0 / 16.0));
    const float ang = t[r] * invf;
    float sn, cs;
    sincosf(ang, &sn, &cs);
    tab[((size_t)r << 5) + (i << 1)]     = cs;
    tab[((size_t)r << 5) + (i << 1) + 1] = sn;
}

// ---------------- qtok build + layernorm -> bf16 ----------------------------
__global__ __launch_bounds__(128) void k_qtok_ln(
    const int* __restrict__ qidx, const float* __restrict__ uemb,
    const float* __restrict__ vpb, const float* __restrict__ w,
    const float* __restrict__ bb, u16* __restrict__ qtok, u16* __restrict__ xn)
{
    const int r = blockIdx.x, tid = threadIdx.x, c0 = tid << 2;
    float4 x;
    if (c0 < 256) {
        x = *(const float4*)&vpb[c0];
    } else {
        const int u = qidx[r];
        x = *(const float4*)&uemb[(size_t)u * 256 + (c0 - 256)];
    }
    ushort4 qo;
    qo.x = f2b(x.x); qo.y = f2b(x.y); qo.z = f2b(x.z); qo.w = f2b(x.w);
    *(ushort4*)&qtok[(size_t)r * 512 + c0] = qo;
    float s  = x.x + x.y + x.z + x.w;
    float s2 = x.x * x.x + x.y * x.y + x.z * x.z + x.w * x.w;
#pragma unroll
    for (int o = 32; o > 0; o >>= 1) { s += __shfl_down(s, o); s2 += __shfl_down(s2, o); }
    __shared__ float buf[4];
    if ((tid & 63) == 0) { buf[(tid >> 6) << 1] = s; buf[((tid >> 6) << 1) + 1] = s2; }
    __syncthreads();
    s = buf[0] + buf[2]; s2 = buf[1] + buf[3];
    const float mu = s * (1.f / 512.f);
    const float rs = rsqrtf(s2 * (1.f / 512.f) - mu * mu + 1e-5f);
    const float4 w4 = *(const float4*)&w[c0];
    const float4 b4 = *(const float4*)&bb[c0];
    ushort4 yo;
    yo.x = f2b((x.x - mu) * rs * w4.x + b4.x);
    yo.y = f2b((x.y - mu) * rs * w4.y + b4.y);
    yo.z = f2b((x.z - mu) * rs * w4.z + b4.z);
    yo.w = f2b((x.w - mu) * rs * w4.w + b4.w);
    *(ushort4*)&xn[(size_t)r * 512 + c0] = yo;
}

// ---------------- layernorm f32-in -> bf16-out ------------------------------
__global__ __launch_bounds__(128) void k_ln_f(
    const float* __restrict__ in, const float* __restrict__ w,
    const float* __restrict__ bb, u16* __restrict__ outp)
{
    const int r = blockIdx.x, tid = threadIdx.x, c0 = tid << 2;
    const float4 x = *(const float4*)&in[(size_t)r * 512 + c0];
    float s  = x.x + x.y + x.z + x.w;
    float s2 = x.x * x.x + x.y * x.y + x.z * x.z + x.w * x.w;
#pragma unroll
    for (int o = 32; o > 0; o >>= 1) { s += __shfl_down(s, o); s2 += __shfl_down(s2, o); }
    __shared__ float buf[4];
    if ((tid & 63) == 0) { buf[(tid >> 6) << 1] = s; buf[((tid >> 6) << 1) + 1] = s2; }
    __syncthreads();
    s = buf[0] + buf[2]; s2 = buf[1] + buf[3];
    const float mu = s * (1.f / 512.f);
    const float rs = rsqrtf(s2 * (1.f / 512.f) - mu * mu + 1e-5f);
    const float4 w4 = *(const float4*)&w[c0];
    const float4 b4 = *(const float4*)&bb[c0];
    ushort4 yo;
    yo.x = f2b((x.x - mu) * rs * w4.x + b4.x);
    yo.y = f2b((x.y - mu) * rs * w4.y + b4.y);
    yo.z = f2b((x.z - mu) * rs * w4.z + b4.z);
    yo.w = f2b((x.w - mu) * rs * w4.w + b4.w);
    *(ushort4*)&outp[(size_t)r * 512 + c0] = yo;
}

// ---------------- layernorm bf16-in -> bf16-out -----------------------------
__global__ __launch_bounds__(128) void k_ln_h(
    const u16* __restrict__ in, const float* __restrict__ w,
    const float* __restrict__ bb, u16* __restrict__ outp)
{
    const int r = blockIdx.x, tid = threadIdx.x, c0 = tid << 2;
    const ushort4 xi = *(const ushort4*)&in[(size_t)r * 512 + c0];
    float4 x;
    x.x = b2f(xi.x); x.y = b2f(xi.y); x.z = b2f(xi.z); x.w = b2f(xi.w);
    float s  = x.x + x.y + x.z + x.w;
    float s2 = x.x * x.x + x.y * x.y + x.z * x.z + x.w * x.w;
#pragma unroll
    for (int o = 32; o > 0; o >>= 1) { s += __shfl_down(s, o); s2 += __shfl_down(s2, o); }
    __shared__ float buf[4];
    if ((tid & 63) == 0) { buf[(tid >> 6) << 1] = s; buf[((tid >> 6) << 1) + 1] = s2; }
    __syncthreads();
    s = buf[0] + buf[2]; s2 = buf[1] + buf[3];
    const float mu = s * (1.f / 512.f);
    const float rs = rsqrtf(s2 * (1.f / 512.f) - mu * mu + 1e-5f);
    const float4 w4 = *(const float4*)&w[c0];
    const float4 b4 = *(const float4*)&bb[c0];
    ushort4 yo;
    yo.x = f2b((x.x - mu) * rs * w4.x + b4.x);
    yo.y = f2b((x.y - mu) * rs * w4.y + b4.y);
    yo.z = f2b((x.z - mu) * rs * w4.z + b4.z);
    yo.w = f2b((x.w - mu) * rs * w4.w + b4.w);
    *(ushort4*)&outp[(size_t)r * 512 + c0] = yo;
}

// ---------------- MFMA GEMM: C[m,n] = sum_k A[m,k]*W[n,k] -------------------
// 128x128 tile, BK=32, 4 waves (2x2), register-staged LDS (r3-proven).
// EPI 0: rope(tab) -> out0 bf16
// EPI 1: rope(tab); c<512 -> out0 (k); c>=512 -> out1 (vT [b,h][d][pos])
// EPI 2: out0 = acc + bias + res (bf16 residual add)
template <int EPI>
__global__ __launch_bounds__(256) void k_mgemm(
    const u16* __restrict__ A, const u16* __restrict__ W,
    const int N, const int K,
    u16* __restrict__ out0, u16* __restrict__ out1,
    const float* __restrict__ bias, const u16* __restrict__ res,
    const float* __restrict__ tab)
{
    __shared__ u16 Al[128 * 32];
    __shared__ u16 Bl[128 * 32];
    const int bm = blockIdx.y << 7, bn = blockIdx.x << 7;
    const int tid = threadIdx.x;
    const int w = tid >> 6, l = tid & 63;
    const int wm = w >> 1, wn = w & 1;
    const int srow = tid >> 2, skq = (tid & 3) << 3;
    const int lr = l & 15, hi = l >> 4;
    const u16* Ap = A + (size_t)(bm + srow) * K + skq;
    const u16* Wp = W + (size_t)(bn + srow) * K + skq;
    f32x4 acc[4][4];
#pragma unroll
    for (int i = 0; i < 4; i++)
#pragma unroll
        for (int j = 0; j < 4; j++)
#pragma unroll
            for (int e = 0; e < 4; e++) acc[i][j][e] = 0.f;
    for (int k0 = 0; k0 < K; k0 += 32) {
        const uint4 a0 = *(const uint4*)(Ap + k0);
        const uint4 a1 = *(const uint4*)(Ap + (size_t)64 * K + k0);
        const uint4 b0 = *(const uint4*)(Wp + k0);
        const uint4 b1 = *(const uint4*)(Wp + (size_t)64 * K + k0);
        __syncthreads();
        *(uint4*)&Al[srow * 32 + skq] = a0;
        *(uint4*)&Al[(srow + 64) * 32 + skq] = a1;
        *(uint4*)&Bl[srow * 32 + skq] = b0;
        *(uint4*)&Bl[(srow + 64) * 32 + skq] = b1;
        __syncthreads();
        bf16x8 av[4], bv[4];
#pragma unroll
        for (int mi = 0; mi < 4; mi++)
            av[mi] = *(const bf16x8*)&Al[(wm * 64 + mi * 16 + lr) * 32 + hi * 8];
#pragma unroll
        for (int nj = 0; nj < 4; nj++)
            bv[nj] = *(const bf16x8*)&Bl[(wn * 64 + nj * 16 + lr) * 32 + hi * 8];
#pragma unroll
        for (int mi = 0; mi < 4; mi++)
#pragma unroll
            for (int nj = 0; nj < 4; nj++)
                acc[mi][nj] = mfma32(av[mi], bv[nj], acc[mi][nj]);
    }
#pragma unroll
    for (int mi = 0; mi < 4; mi++) {
#pragma unroll
        for (int nj = 0; nj < 4; nj++) {
            const int c = bn + wn * 64 + nj * 16 + lr;
#pragma unroll
            for (int j = 0; j < 4; j++) {
                const int r = bm + wm * 64 + mi * 16 + hi * 4 + j;
                const float x = acc[mi][nj][j];
                if (EPI == 2) {
                    const float y = x + bias[c] + b2f(res[(size_t)r * 512 + c]);
                    out0[(size_t)r * 512 + c] = f2b(y);
                } else {
                    const float p = __shfl_xor(x, 1);
                    const int ci = c & 63;
                    float y = x;
                    if (ci < 32) {
                        const int ii = ci >> 1;
                        const float cc = tab[((size_t)r << 5) + (ii << 1)];
                        const float ss = tab[((size_t)r << 5) + (ii << 1) + 1];
                        y = (c & 1) ? fmaf(x, cc, p * ss) : fmaf(x, cc, -p * ss);
                    }
                    if (EPI == 0) {
                        out0[(size_t)r * 512 + c] = f2b(y);
                    } else {
                        if (c < 512) {
                            out0[(size_t)r * 512 + c] = f2b(y);
                        } else {
                            const int d = c - 512, hh = d >> 6, dd = d & 63;
                            const int bq = r >> 10, pos = r & 1023;
                            out1[(((size_t)(bq * 8 + hh)) * 64 + dd) * 1024 + pos] = f2b(y);
                        }
                    }
                }
            }
        }
    }
}

// ---------------- FFN1: dual MFMA GEMM + exact gelu gate --------------------
__global__ __launch_bounds__(256) void k_mffn1(
    const u16* __restrict__ A, const u16* __restrict__ W1,
    const float* __restrict__ b1, u16* __restrict__ ag)
{
    __shared__ u16 Al[128 * 32];
    __shared__ u16 Bl[128 * 32];
    const int bm = blockIdx.y << 7, bn = blockIdx.x << 6;
    const int tid = threadIdx.x;
    const int w = tid >> 6, l = tid & 63;
    const int wm = w >> 1, wn = w & 1;
    const int srow = tid >> 2, skq = (tid & 3) << 3;
    const int lr = l & 15, hi = l >> 4;
    const u16* Ap  = A  + (size_t)(bm + srow) * 512 + skq;
    const u16* Wap = W1 + (size_t)(bn + srow) * 512 + skq;
    const u16* Wgp = W1 + (size_t)(2048 + bn + srow) * 512 + skq;
    f32x4 acca[4][2], accg[4][2];
#pragma unroll
    for (int i = 0; i < 4; i++)
#pragma unroll
        for (int j = 0; j < 2; j++)
#pragma unroll
            for (int e = 0; e < 4; e++) { acca[i][j][e] = 0.f; accg[i][j][e] = 0.f; }
    for (int k0 = 0; k0 < 512; k0 += 32) {
        const uint4 a0 = *(const uint4*)(Ap + k0);
        const uint4 a1 = *(const uint4*)(Ap + (size_t)64 * 512 + k0);
        const uint4 w0 = *(const uint4*)(Wap + k0);
        const uint4 w1v = *(const uint4*)(Wgp + k0);
        __syncthreads();
        *(uint4*)&Al[srow * 32 + skq] = a0;
        *(uint4*)&Al[(srow + 64) * 32 + skq] = a1;
        *(uint4*)&Bl[srow * 32 + skq] = w0;
        *(uint4*)&Bl[(srow + 64) * 32 + skq] = w1v;
        __syncthreads();
        bf16x8 av[4], ba[2], bg[2];
#pragma unroll
        for (int mi = 0; mi < 4; mi++)
            av[mi] = *(const bf16x8*)&Al[(wm * 64 + mi * 16 + lr) * 32 + hi * 8];
#pragma unroll
        for (int nj = 0; nj < 2; nj++) {
            ba[nj] = *(const bf16x8*)&Bl[(wn * 32 + nj * 16 + lr) * 32 + hi * 8];
            bg[nj] = *(const bf16x8*)&Bl[(wn * 32 + nj * 16 + lr + 64) * 32 + hi * 8];
        }
#pragma unroll
        for (int mi = 0; mi < 4; mi++)
#pragma unroll
            for (int nj = 0; nj < 2; nj++) {
                acca[mi][nj] = mfma32(av[mi], ba[nj], acca[mi][nj]);
                accg[mi][nj] = mfma32(av[mi], bg[nj], accg[mi][nj]);
            }
    }
#pragma unroll
    for (int mi = 0; mi < 4; mi++)
#pragma unroll
        for (int nj = 0; nj < 2; nj++) {
            const int c = bn + wn * 32 + nj * 16 + lr;
#pragma unroll
            for (int j = 0; j < 4; j++) {
                const int r = bm + wm * 64 + mi * 16 + hi * 4 + j;
                const float a = acca[mi][nj][j] + b1[c];
                const float g = accg[mi][nj][j] + b1[2048 + c];
                const float ge = 0.5f * g * (1.f + erff(g * 0.70710678118654752f));
                ag[(size_t)r * 2048 + c] = f2b(a * ge);
            }
        }
}

// ---------------- attention: builtin-MFMA only, LDS-free --------------------
// grid (CQ/64, 8), 256 thr = 4 waves, wave = 16 q rows. 64-key chunks.
// QK^T: st[t] = mfma32(K-frag, Q-frag) -> lane owns q=lr, keys t*16+hi*4+j.
// Softmax in-register (2 shfl_xor reductions).
// PV: O += V^T x P^T via mfma32: V-frag = contiguous bf16x8 from vT (global),
// P-frag built from softmax regs by lane shuffles:
//   Bfrag[ks][e] = P[q=lr][pos=ks*32+hi*8+e]
//                = lane(lr, (hi&1)*2+(e>>2)) . P64[ks*2+(hi>>1)]
__global__ __launch_bounds__(256) void k_mattn(
    const u16* __restrict__ q, const u16* __restrict__ kbuf,
    const u16* __restrict__ vT, const float* __restrict__ tab,
    u16* __restrict__ ao, const int rowbase)
{
    const int h = blockIdx.y, tid = threadIdx.x;
    const int w = tid >> 6, l = tid & 63;
    const int lr = l & 15, hi = l >> 4;
    const int qr = blockIdx.x * 64 + w * 16 + lr;       // chunk-local q row
    const int b = (rowbase + blockIdx.x * 64) >> 12;    // batch
    const bf16x8 qf0 = *(const bf16x8*)&q[(size_t)qr * 512 + h * 64 + hi * 8];
    const bf16x8 qf1 = *(const bf16x8*)&q[(size_t)qr * 512 + h * 64 + hi * 8 + 32];
    const u16* Kp = kbuf + (size_t)b * 524288 + h * 64;
    const u16* Vp = vT + ((size_t)(b * 8 + h)) * 65536;
    const int g2 = (hi & 1) * 2;          // source hi group for e=0..3
    const int srcA = lr + (g2 << 4);
    const int srcB = srcA + 16;
    const bool up = (hi >> 1) != 0;
    f32x4 accO[4];
#pragma unroll
    for (int dj = 0; dj < 4; dj++)
#pragma unroll
        for (int e = 0; e < 4; e++) accO[dj][e] = 0.f;
    float mrun = -1e30f, lrun = 0.f;
    for (int kc = 0; kc < 1024; kc += 64) {
        f32x4 st[4];
#pragma unroll
        for (int t = 0; t < 4; t++) {
#pragma unroll
            for (int e = 0; e < 4; e++) st[t][e] = 0.f;
            const size_t krow = (size_t)(kc + t * 16 + lr) * 512 + hi * 8;
            const bf16x8 kf0 = *(const bf16x8*)&Kp[krow];
            const bf16x8 kf1 = *(const bf16x8*)&Kp[krow + 32];
            st[t] = mfma32(kf0, qf0, st[t]);
            st[t] = mfma32(kf1, qf1, st[t]);
        }
        float mx = -1e30f;
#pragma unroll
        for (int t = 0; t < 4; t++)
#pragma unroll
            for (int j = 0; j < 4; j++) { st[t][j] *= 0.125f; mx = fmaxf(mx, st[t][j]); }
        mx = fmaxf(mx, __shfl_xor(mx, 16));
        mx = fmaxf(mx, __shfl_xor(mx, 32));
        const float mnew = fmaxf(mrun, mx);
        const float alpha = expf(mrun - mnew);
        float ps = 0.f;
        unsigned P64[4][2];               // per t: packed bf16 x4 (j=0..3)
#pragma unroll
        for (int t = 0; t < 4; t++) {
            const float p0 = expf(st[t][0] - mnew);
            const float p1 = expf(st[t][1] - mnew);
            const float p2 = expf(st[t][2] - mnew);
            const float p3 = expf(st[t][3] - mnew);
            ps += (p0 + p1) + (p2 + p3);
            P64[t][0] = (unsigned)f2b(p0) | ((unsigned)f2b(p1) << 16);
            P64[t][1] = (unsigned)f2b(p2) | ((unsigned)f2b(p3) << 16);
        }
        ps += __shfl_xor(ps, 16);
        ps += __shfl_xor(ps, 32);
        lrun = lrun * alpha + ps;
        mrun = mnew;
#pragma unroll
        for (int dj = 0; dj < 4; dj++)
#pragma unroll
            for (int e = 0; e < 4; e++) accO[dj][e] *= alpha;
        // build P fragments for the two 32-wide subtiles
        bf16x8 pfrag[2];
#pragma unroll
        for (int ks = 0; ks < 2; ks++) {
            const unsigned c0x = P64[ks * 2 + 0][0], c0y = P64[ks * 2 + 0][1];
            const unsigned c1x = P64[ks * 2 + 1][0], c1y = P64[ks * 2 + 1][1];
            const unsigned a0x = (unsigned)__shfl((int)c0x, srcA);
            const unsigned a0y = (unsigned)__shfl((int)c0y, srcA);
            const unsigned a1x = (unsigned)__shfl((int)c1x, srcA);
            const unsigned a1y = (unsigned)__shfl((int)c1y, srcA);
            const unsigned b0x = (unsigned)__shfl((int)c0x, srcB);
            const unsigned b0y = (unsigned)__shfl((int)c0y, srcB);
            const unsigned b1x = (unsigned)__shfl((int)c1x, srcB);
            const unsigned b1y = (unsigned)__shfl((int)c1y, srcB);
            union { unsigned u[4]; bf16x8 v; } pk;
            pk.u[0] = up ? a1x : a0x;
            pk.u[1] = up ? a1y : a0y;
            pk.u[2] = up ? b1x : b0x;
            pk.u[3] = up ? b1y : b0y;
            pfrag[ks] = pk.v;
        }
#pragma unroll
        for (int dj = 0; dj < 4; dj++)
#pragma unroll
            for (int ks = 0; ks < 2; ks++) {
                const bf16x8 vf = *(const bf16x8*)
                    &Vp[(size_t)(dj * 16 + lr) * 1024 + kc + ks * 32 + hi * 8];
                accO[dj] = mfma32(vf, pfrag[ks], accO[dj]);
            }
    }
    const float invl = 1.f / lrun;
#pragma unroll
    for (int dj = 0; dj < 4; dj++) {
        const int d0 = dj * 16 + hi * 4;
        float y[4];
#pragma unroll
        for (int pp = 0; pp < 2; pp++) {
            const float x0 = accO[dj][2 * pp] * invl;
            const float x1 = accO[dj][2 * pp + 1] * invl;
            const int ii = (d0 >> 1) + pp;
            if (ii < 16) {
                const float cc = tab[((size_t)qr << 5) + (ii << 1)];
                const float ss = tab[((size_t)qr << 5) + (ii << 1) + 1];
                y[2 * pp]     = fmaf(x0, cc, x1 * ss);    // inverse rotation
                y[2 * pp + 1] = fmaf(x1, cc, -x0 * ss);
            } else {
                y[2 * pp] = x0; y[2 * pp + 1] = x1;
            }
        }
        ushort4 o;
        o.x = f2b(y[0]); o.y = f2b(y[1]); o.z = f2b(y[2]); o.w = f2b(y[3]);
        *(ushort4*)&ao[(size_t)qr * 512 + h * 64 + d0] = o;
    }
}

// ---------------- final: LN + dot with wproj (bf16 in, f32 out) -------------
__global__ __launch_bounds__(128) void k_final(
    const u16* __restrict__ dec, const float* __restrict__ w,
    const float* __restrict__ bb, const float* __restrict__ wproj,
    const float* __restrict__ bproj, float* __restrict__ out)
{
    const int r = blockIdx.x, tid = threadIdx.x, c0 = tid << 2;
    const ushort4 xi = *(const ushort4*)&dec[(size_t)r * 512 + c0];
    float4 x;
    x.x = b2f(xi.x); x.y = b2f(xi.y); x.z = b2f(xi.z); x.w = b2f(xi.w);
    float s  = x.x + x.y + x.z + x.w;
    float s2 = x.x * x.x + x.y * x.y + x.z * x.z + x.w * x.w;
#pragma unroll
    for (int o = 32; o > 0; o >>= 1) { s += __shfl_down(s, o); s2 += __shfl_down(s2, o); }
    __shared__ float buf[4];
    if ((tid & 63) == 0) { buf[(tid >> 6) << 1] = s; buf[((tid >> 6) << 1) + 1] = s2; }
    __syncthreads();
    s = buf[0] + buf[2]; s2 = buf[1] + buf[3];
    const float mu = s * (1.f / 512.f);
    const float rs = rsqrtf(s2 * (1.f / 512.f) - mu * mu + 1e-5f);
    const float4 w4 = *(const float4*)&w[c0];
    const float4 b4 = *(const float4*)&bb[c0];
    const float4 p4 = *(const float4*)&wproj[c0];
    float part = ((x.x - mu) * rs * w4.x + b4.x) * p4.x
               + ((x.y - mu) * rs * w4.y + b4.y) * p4.y
               + ((x.z - mu) * rs * w4.z + b4.z) * p4.z
               + ((x.w - mu) * rs * w4.w + b4.w) * p4.w;
#pragma unroll
    for (int o = 32; o > 0; o >>= 1) part += __shfl_down(part, o);
    __shared__ float buf2[2];
    if ((tid & 63) == 0) buf2[tid >> 6] = part;
    __syncthreads();
    if (tid == 0) out[r] = buf2[0] + buf2[1] + bproj[0];
}

// ---------------------------------------------------------------------------
extern "C" void kernel_launch(void* const* d_in, const int* in_sizes, int n_in,
                              void* d_out, int out_size, void* d_ws, size_t ws_size,
                              hipStream_t stream)
{
    (void)in_sizes; (void)n_in; (void)out_size;
    const float* enc  = (const float*)d_in[0];
    const float* lts  = (const float*)d_in[1];
    const int*   qidx = (const int*)  d_in[2];
    const float* qts  = (const float*)d_in[3];
    const float* uemb = (const float*)d_in[4];
    const float* vpb  = (const float*)d_in[6];
    const float* canw = (const float*)d_in[7];
    const float* canb = (const float*)d_in[8];
    const float* ccw  = (const float*)d_in[9];
    const float* ccb  = (const float*)d_in[10];
    const float* wq   = (const float*)d_in[11];
    const float* wkv  = (const float*)d_in[12];
    const float* wo   = (const float*)d_in[13];
    const float* bo   = (const float*)d_in[14];
    const float* flnw = (const float*)d_in[15];
    const float* flnb = (const float*)d_in[16];
    const float* w1   = (const float*)d_in[17];
    const float* b1   = (const float*)d_in[18];
    const float* w2   = (const float*)d_in[19];
    const float* b2   = (const float*)d_in[20];
    const float* olnw = (const float*)d_in[21];
    const float* olnb = (const float*)d_in[22];
    const float* wpj  = (const float*)d_in[23];
    const float* bpj  = (const float*)d_in[24];
    float* outp = (float*)d_out;

    // workspace: f32 tabs, then bf16 region
    float* tabq = (float*)d_ws;              // 16384*32
    float* tabl = tabq + 524288;             // 4096*32
    u16* wqb  = (u16*)(tabl + 131072);       // 512*512
    u16* wkvb = wqb + 262144;                // 1024*512
    u16* wob  = wkvb + 524288;               // 512*512
    u16* w1b  = wob + 262144;                // 4096*512
    u16* w2b  = w1b + 2097152;               // 512*2048
    u16* cn   = w2b + 1048576;               // 4096*512
    u16* kb   = cn + 2097152;                // 4096*512
    u16* vT   = kb + 2097152;                // 4*8*64*1024
    const size_t base_b = 2621440ull + 20971520ull;       // tabs + bf16 shared
    int CQ = 16384;
    while (CQ > 512 &&
           base_b + (size_t)CQ * 5120 + (size_t)(CQ < 4096 ? CQ : 4096) * 4096 > ws_size)
        CQ >>= 1;
    int SF = CQ;
    while (SF > 512 && base_b + (size_t)CQ * 5120 + (size_t)SF * 4096 > ws_size)
        SF >>= 1;
    u16* qtokC = vT + 2097152;               // CQ*512
    u16* xnC   = qtokC + (size_t)CQ * 512;   // CQ*512 (reused: ln_dec)
    u16* qC    = xnC + (size_t)CQ * 512;     // CQ*512 (reused: dec_final)
    u16* aoC   = qC + (size_t)CQ * 512;      // CQ*512
    u16* d2C   = aoC + (size_t)CQ * 512;     // CQ*512
    u16* agC   = d2C + (size_t)CQ * 512;     // SF*2048

    k_cvt<<<256, 256, 0, stream>>>(wq, wqb, 262144);
    k_cvt<<<512, 256, 0, stream>>>(wkv, wkvb, 524288);
    k_cvt<<<256, 256, 0, stream>>>(wo, wob, 262144);
    k_cvt<<<2048, 256, 0, stream>>>(w1, w1b, 2097152);
    k_cvt<<<1024, 256, 0, stream>>>(w2, w2b, 1048576);
    k_rope_tab16<<<1024, 256, 0, stream>>>(qts, tabq, 16384);
    k_rope_tab16<<<256, 256, 0, stream>>>(lts, tabl, 4096);
    k_ln_f<<<4096, 128, 0, stream>>>(enc, ccw, ccb, cn);
    k_mgemm<1><<<dim3(8, 32), 256, 0, stream>>>(cn, wkvb, 1024, 512,
                                                kb, vT, nullptr, nullptr, tabl);

    for (int g0 = 0; g0 < 16384; g0 += CQ) {
        const float* tabc = tabq + (size_t)g0 * 32;
        k_qtok_ln<<<CQ, 128, 0, stream>>>(qidx + g0, uemb, vpb, canw, canb,
                                          qtokC, xnC);
        k_mgemm<0><<<dim3(4, CQ / 128), 256, 0, stream>>>(xnC, wqb, 512, 512,
                                                          qC, nullptr, nullptr, nullptr, tabc);
        k_mattn<<<dim3(CQ / 64, 8), 256, 0, stream>>>(qC, kb, vT, tabc, aoC, g0);
        k_mgemm<2><<<dim3(4, CQ / 128), 256, 0, stream>>>(aoC, wob, 512, 512,
                                                          d2C, nullptr, bo, qtokC, nullptr);
        k_ln_h<<<CQ, 128, 0, stream>>>(d2C, flnw, flnb, xnC);
        for (int f0 = 0; f0 < CQ; f0 += SF) {
            k_mffn1<<<dim3(32, SF / 128), 256, 0, stream>>>(xnC + (size_t)f0 * 512,
                                                            w1b, b1, agC);
            k_mgemm<2><<<dim3(4, SF / 128), 256, 0, stream>>>(agC, w2b, 512, 2048,
                                                              qC + (size_t)f0 * 512, nullptr,
                                                              b2, d2C + (size_t)f0 * 512, nullptr);
            k_final<<<SF, 128, 0, stream>>>(qC + (size_t)f0 * 512, olnw, olnb,
                                            wpj, bpj, outp + g0 + f0);
        }
    }
}

// Round 9
// 512.692 us; speedup vs baseline: 5.8399x; 1.0037x over previous
//
#include <hip/hip_runtime.h>
#include <math.h>

// ---------------------------------------------------------------------------
// MaskingDecoder bf16-MFMA v7: r8 (514us PASS) + attention softmax/VALU diet:
//   - __expf (v_exp_f32) instead of libm expf
//   - 1/sqrt(DH) folded into K at the kv-projection epilogue
//   - defer-max (THR=8, wave-uniform __all) skips most rescales
//   - register double-buffered K prefetch hides L2 back-edge latency
// GEMMs byte-identical to r8 except K pre-scale in EPI1.
// ---------------------------------------------------------------------------

typedef unsigned short u16;
typedef __attribute__((ext_vector_type(8))) short bf16x8;
typedef __attribute__((ext_vector_type(4))) float f32x4;

__device__ __forceinline__ u16 f2b(float x) {
    union { float f; unsigned u; } v; v.f = x;
    unsigned r = v.u + 0x7fffu + ((v.u >> 16) & 1u);
    return (u16)(r >> 16);
}
__device__ __forceinline__ float b2f(u16 h) {
    union { unsigned u; float f; } v; v.u = ((unsigned)h) << 16;
    return v.f;
}
__device__ __forceinline__ f32x4 mfma32(bf16x8 a, bf16x8 b, f32x4 c) {
    return __builtin_amdgcn_mfma_f32_16x16x32_bf16(a, b, c, 0, 0, 0);
}

// ---------------- f32 -> bf16 weight convert --------------------------------
__global__ __launch_bounds__(256) void k_cvt(const float* __restrict__ in,
                                             u16* __restrict__ out, const int n)
{
    const int i = (blockIdx.x * 256 + threadIdx.x) * 4;
    if (i >= n) return;
    const float4 v = *(const float4*)&in[i];
    ushort4 o;
    o.x = f2b(v.x); o.y = f2b(v.y); o.z = f2b(v.z); o.w = f2b(v.w);
    *(ushort4*)&out[i] = o;
}

// ---------------- rope table: 16 (cos,sin) pairs per row --------------------
__global__ void k_rope_tab16(const float* __restrict__ t, float* __restrict__ tab,
                             const int n)
{
    const int idx = blockIdx.x * 256 + threadIdx.x;
    if (idx >= n * 16) return;
    const int r = idx >> 4, i = idx & 15;
    const float b0 = (float)(1e-4 / 2.0627);
    const float a0 = (float)(2.0 * 3.14159265358979323846 / 1e-4);
    const float invf = a0 * (float)pow((double)b0, (double)i * (1.0 / 16.0));
    const float ang = t[r] * invf;
    float sn, cs;
    sincosf(ang, &sn, &cs);
    tab[((size_t)r << 5) + (i << 1)]     = cs;
    tab[((size_t)r << 5) + (i << 1) + 1] = sn;
}

// ---------------- qtok build + layernorm -> bf16 ----------------------------
__global__ __launch_bounds__(128) void k_qtok_ln(
    const int* __restrict__ qidx, const float* __restrict__ uemb,
    const float* __restrict__ vpb, const float* __restrict__ w,
    const float* __restrict__ bb, u16* __restrict__ qtok, u16* __restrict__ xn)
{
    const int r = blockIdx.x, tid = threadIdx.x, c0 = tid << 2;
    float4 x;
    if (c0 < 256) {
        x = *(const float4*)&vpb[c0];
    } else {
        const int u = qidx[r];
        x = *(const float4*)&uemb[(size_t)u * 256 + (c0 - 256)];
    }
    ushort4 qo;
    qo.x = f2b(x.x); qo.y = f2b(x.y); qo.z = f2b(x.z); qo.w = f2b(x.w);
    *(ushort4*)&qtok[(size_t)r * 512 + c0] = qo;
    float s  = x.x + x.y + x.z + x.w;
    float s2 = x.x * x.x + x.y * x.y + x.z * x.z + x.w * x.w;
#pragma unroll
    for (int o = 32; o > 0; o >>= 1) { s += __shfl_down(s, o); s2 += __shfl_down(s2, o); }
    __shared__ float buf[4];
    if ((tid & 63) == 0) { buf[(tid >> 6) << 1] = s; buf[((tid >> 6) << 1) + 1] = s2; }
    __syncthreads();
    s = buf[0] + buf[2]; s2 = buf[1] + buf[3];
    const float mu = s * (1.f / 512.f);
    const float rs = rsqrtf(s2 * (1.f / 512.f) - mu * mu + 1e-5f);
    const float4 w4 = *(const float4*)&w[c0];
    const float4 b4 = *(const float4*)&bb[c0];
    ushort4 yo;
    yo.x = f2b((x.x - mu) * rs * w4.x + b4.x);
    yo.y = f2b((x.y - mu) * rs * w4.y + b4.y);
    yo.z = f2b((x.z - mu) * rs * w4.z + b4.z);
    yo.w = f2b((x.w - mu) * rs * w4.w + b4.w);
    *(ushort4*)&xn[(size_t)r * 512 + c0] = yo;
}

// ---------------- layernorm f32-in -> bf16-out ------------------------------
__global__ __launch_bounds__(128) void k_ln_f(
    const float* __restrict__ in, const float* __restrict__ w,
    const float* __restrict__ bb, u16* __restrict__ outp)
{
    const int r = blockIdx.x, tid = threadIdx.x, c0 = tid << 2;
    const float4 x = *(const float4*)&in[(size_t)r * 512 + c0];
    float s  = x.x + x.y + x.z + x.w;
    float s2 = x.x * x.x + x.y * x.y + x.z * x.z + x.w * x.w;
#pragma unroll
    for (int o = 32; o > 0; o >>= 1) { s += __shfl_down(s, o); s2 += __shfl_down(s2, o); }
    __shared__ float buf[4];
    if ((tid & 63) == 0) { buf[(tid >> 6) << 1] = s; buf[((tid >> 6) << 1) + 1] = s2; }
    __syncthreads();
    s = buf[0] + buf[2]; s2 = buf[1] + buf[3];
    const float mu = s * (1.f / 512.f);
    const float rs = rsqrtf(s2 * (1.f / 512.f) - mu * mu + 1e-5f);
    const float4 w4 = *(const float4*)&w[c0];
    const float4 b4 = *(const float4*)&bb[c0];
    ushort4 yo;
    yo.x = f2b((x.x - mu) * rs * w4.x + b4.x);
    yo.y = f2b((x.y - mu) * rs * w4.y + b4.y);
    yo.z = f2b((x.z - mu) * rs * w4.z + b4.z);
    yo.w = f2b((x.w - mu) * rs * w4.w + b4.w);
    *(ushort4*)&outp[(size_t)r * 512 + c0] = yo;
}

// ---------------- layernorm bf16-in -> bf16-out -----------------------------
__global__ __launch_bounds__(128) void k_ln_h(
    const u16* __restrict__ in, const float* __restrict__ w,
    const float* __restrict__ bb, u16* __restrict__ outp)
{
    const int r = blockIdx.x, tid = threadIdx.x, c0 = tid << 2;
    const ushort4 xi = *(const ushort4*)&in[(size_t)r * 512 + c0];
    float4 x;
    x.x = b2f(xi.x); x.y = b2f(xi.y); x.z = b2f(xi.z); x.w = b2f(xi.w);
    float s  = x.x + x.y + x.z + x.w;
    float s2 = x.x * x.x + x.y * x.y + x.z * x.z + x.w * x.w;
#pragma unroll
    for (int o = 32; o > 0; o >>= 1) { s += __shfl_down(s, o); s2 += __shfl_down(s2, o); }
    __shared__ float buf[4];
    if ((tid & 63) == 0) { buf[(tid >> 6) << 1] = s; buf[((tid >> 6) << 1) + 1] = s2; }
    __syncthreads();
    s = buf[0] + buf[2]; s2 = buf[1] + buf[3];
    const float mu = s * (1.f / 512.f);
    const float rs = rsqrtf(s2 * (1.f / 512.f) - mu * mu + 1e-5f);
    const float4 w4 = *(const float4*)&w[c0];
    const float4 b4 = *(const float4*)&bb[c0];
    ushort4 yo;
    yo.x = f2b((x.x - mu) * rs * w4.x + b4.x);
    yo.y = f2b((x.y - mu) * rs * w4.y + b4.y);
    yo.z = f2b((x.z - mu) * rs * w4.z + b4.z);
    yo.w = f2b((x.w - mu) * rs * w4.w + b4.w);
    *(ushort4*)&outp[(size_t)r * 512 + c0] = yo;
}

// ---------------- MFMA GEMM: C[m,n] = sum_k A[m,k]*W[n,k] -------------------
// 128x128 tile, BK=32, 4 waves (2x2), register-staged LDS (r3-proven).
// EPI 0: rope(tab) -> out0 bf16
// EPI 1: rope(tab); c<512 -> out0 (k, pre-scaled by 1/8); c>=512 -> out1 (vT)
// EPI 2: out0 = acc + bias + res (bf16 residual add)
template <int EPI>
__global__ __launch_bounds__(256) void k_mgemm(
    const u16* __restrict__ A, const u16* __restrict__ W,
    const int N, const int K,
    u16* __restrict__ out0, u16* __restrict__ out1,
    const float* __restrict__ bias, const u16* __restrict__ res,
    const float* __restrict__ tab)
{
    __shared__ u16 Al[128 * 32];
    __shared__ u16 Bl[128 * 32];
    const int bm = blockIdx.y << 7, bn = blockIdx.x << 7;
    const int tid = threadIdx.x;
    const int w = tid >> 6, l = tid & 63;
    const int wm = w >> 1, wn = w & 1;
    const int srow = tid >> 2, skq = (tid & 3) << 3;
    const int lr = l & 15, hi = l >> 4;
    const u16* Ap = A + (size_t)(bm + srow) * K + skq;
    const u16* Wp = W + (size_t)(bn + srow) * K + skq;
    f32x4 acc[4][4];
#pragma unroll
    for (int i = 0; i < 4; i++)
#pragma unroll
        for (int j = 0; j < 4; j++)
#pragma unroll
            for (int e = 0; e < 4; e++) acc[i][j][e] = 0.f;
    for (int k0 = 0; k0 < K; k0 += 32) {
        const uint4 a0 = *(const uint4*)(Ap + k0);
        const uint4 a1 = *(const uint4*)(Ap + (size_t)64 * K + k0);
        const uint4 b0 = *(const uint4*)(Wp + k0);
        const uint4 b1 = *(const uint4*)(Wp + (size_t)64 * K + k0);
        __syncthreads();
        *(uint4*)&Al[srow * 32 + skq] = a0;
        *(uint4*)&Al[(srow + 64) * 32 + skq] = a1;
        *(uint4*)&Bl[srow * 32 + skq] = b0;
        *(uint4*)&Bl[(srow + 64) * 32 + skq] = b1;
        __syncthreads();
        bf16x8 av[4], bv[4];
#pragma unroll
        for (int mi = 0; mi < 4; mi++)
            av[mi] = *(const bf16x8*)&Al[(wm * 64 + mi * 16 + lr) * 32 + hi * 8];
#pragma unroll
        for (int nj = 0; nj < 4; nj++)
            bv[nj] = *(const bf16x8*)&Bl[(wn * 64 + nj * 16 + lr) * 32 + hi * 8];
#pragma unroll
        for (int mi = 0; mi < 4; mi++)
#pragma unroll
            for (int nj = 0; nj < 4; nj++)
                acc[mi][nj] = mfma32(av[mi], bv[nj], acc[mi][nj]);
    }
#pragma unroll
    for (int mi = 0; mi < 4; mi++) {
#pragma unroll
        for (int nj = 0; nj < 4; nj++) {
            const int c = bn + wn * 64 + nj * 16 + lr;
#pragma unroll
            for (int j = 0; j < 4; j++) {
                const int r = bm + wm * 64 + mi * 16 + hi * 4 + j;
                const float x = acc[mi][nj][j];
                if (EPI == 2) {
                    const float y = x + bias[c] + b2f(res[(size_t)r * 512 + c]);
                    out0[(size_t)r * 512 + c] = f2b(y);
                } else {
                    const float p = __shfl_xor(x, 1);
                    const int ci = c & 63;
                    float y = x;
                    if (ci < 32) {
                        const int ii = ci >> 1;
                        const float cc = tab[((size_t)r << 5) + (ii << 1)];
                        const float ss = tab[((size_t)r << 5) + (ii << 1) + 1];
                        y = (c & 1) ? fmaf(x, cc, p * ss) : fmaf(x, cc, -p * ss);
                    }
                    if (EPI == 0) {
                        out0[(size_t)r * 512 + c] = f2b(y);
                    } else {
                        if (c < 512) {
                            out0[(size_t)r * 512 + c] = f2b(y * 0.125f);  // fold DH^-0.5
                        } else {
                            const int d = c - 512, hh = d >> 6, dd = d & 63;
                            const int bq = r >> 10, pos = r & 1023;
                            out1[(((size_t)(bq * 8 + hh)) * 64 + dd) * 1024 + pos] = f2b(y);
                        }
                    }
                }
            }
        }
    }
}

// ---------------- FFN1: dual MFMA GEMM + exact gelu gate --------------------
__global__ __launch_bounds__(256) void k_mffn1(
    const u16* __restrict__ A, const u16* __restrict__ W1,
    const float* __restrict__ b1, u16* __restrict__ ag)
{
    __shared__ u16 Al[128 * 32];
    __shared__ u16 Bl[128 * 32];
    const int bm = blockIdx.y << 7, bn = blockIdx.x << 6;
    const int tid = threadIdx.x;
    const int w = tid >> 6, l = tid & 63;
    const int wm = w >> 1, wn = w & 1;
    const int srow = tid >> 2, skq = (tid & 3) << 3;
    const int lr = l & 15, hi = l >> 4;
    const u16* Ap  = A  + (size_t)(bm + srow) * 512 + skq;
    const u16* Wap = W1 + (size_t)(bn + srow) * 512 + skq;
    const u16* Wgp = W1 + (size_t)(2048 + bn + srow) * 512 + skq;
    f32x4 acca[4][2], accg[4][2];
#pragma unroll
    for (int i = 0; i < 4; i++)
#pragma unroll
        for (int j = 0; j < 2; j++)
#pragma unroll
            for (int e = 0; e < 4; e++) { acca[i][j][e] = 0.f; accg[i][j][e] = 0.f; }
    for (int k0 = 0; k0 < 512; k0 += 32) {
        const uint4 a0 = *(const uint4*)(Ap + k0);
        const uint4 a1 = *(const uint4*)(Ap + (size_t)64 * 512 + k0);
        const uint4 w0 = *(const uint4*)(Wap + k0);
        const uint4 w1v = *(const uint4*)(Wgp + k0);
        __syncthreads();
        *(uint4*)&Al[srow * 32 + skq] = a0;
        *(uint4*)&Al[(srow + 64) * 32 + skq] = a1;
        *(uint4*)&Bl[srow * 32 + skq] = w0;
        *(uint4*)&Bl[(srow + 64) * 32 + skq] = w1v;
        __syncthreads();
        bf16x8 av[4], ba[2], bg[2];
#pragma unroll
        for (int mi = 0; mi < 4; mi++)
            av[mi] = *(const bf16x8*)&Al[(wm * 64 + mi * 16 + lr) * 32 + hi * 8];
#pragma unroll
        for (int nj = 0; nj < 2; nj++) {
            ba[nj] = *(const bf16x8*)&Bl[(wn * 32 + nj * 16 + lr) * 32 + hi * 8];
            bg[nj] = *(const bf16x8*)&Bl[(wn * 32 + nj * 16 + lr + 64) * 32 + hi * 8];
        }
#pragma unroll
        for (int mi = 0; mi < 4; mi++)
#pragma unroll
            for (int nj = 0; nj < 2; nj++) {
                acca[mi][nj] = mfma32(av[mi], ba[nj], acca[mi][nj]);
                accg[mi][nj] = mfma32(av[mi], bg[nj], accg[mi][nj]);
            }
    }
#pragma unroll
    for (int mi = 0; mi < 4; mi++)
#pragma unroll
        for (int nj = 0; nj < 2; nj++) {
            const int c = bn + wn * 32 + nj * 16 + lr;
#pragma unroll
            for (int j = 0; j < 4; j++) {
                const int r = bm + wm * 64 + mi * 16 + hi * 4 + j;
                const float a = acca[mi][nj][j] + b1[c];
                const float g = accg[mi][nj][j] + b1[2048 + c];
                const float ge = 0.5f * g * (1.f + erff(g * 0.70710678118654752f));
                ag[(size_t)r * 2048 + c] = f2b(a * ge);
            }
        }
}

// ---------------- attention: builtin-MFMA only, LDS-free --------------------
// grid (CQ/64, 8), 256 thr = 4 waves, wave = 16 q rows. 64-key chunks.
// K pre-scaled by 1/8 so st needs no scale. Register double-buffered K
// prefetch; defer-max (THR=8); __expf softmax; shuffled P fragments; PV via
// builtin mfma32 with contiguous V^T loads.
__global__ __launch_bounds__(256) void k_mattn(
    const u16* __restrict__ q, const u16* __restrict__ kbuf,
    const u16* __restrict__ vT, const float* __restrict__ tab,
    u16* __restrict__ ao, const int rowbase)
{
    const int h = blockIdx.y, tid = threadIdx.x;
    const int w = tid >> 6, l = tid & 63;
    const int lr = l & 15, hi = l >> 4;
    const int qr = blockIdx.x * 64 + w * 16 + lr;       // chunk-local q row
    const int b = (rowbase + blockIdx.x * 64) >> 12;    // batch
    const bf16x8 qf0 = *(const bf16x8*)&q[(size_t)qr * 512 + h * 64 + hi * 8];
    const bf16x8 qf1 = *(const bf16x8*)&q[(size_t)qr * 512 + h * 64 + hi * 8 + 32];
    const u16* Kp = kbuf + (size_t)b * 524288 + h * 64;
    const u16* Vp = vT + ((size_t)(b * 8 + h)) * 65536;
    const int g2 = (hi & 1) * 2;          // source hi group for e=0..3
    const int srcA = lr + (g2 << 4);
    const int srcB = srcA + 16;
    const bool up = (hi >> 1) != 0;
    f32x4 accO[4];
#pragma unroll
    for (int dj = 0; dj < 4; dj++)
#pragma unroll
        for (int e = 0; e < 4; e++) accO[dj][e] = 0.f;
    float mrun = -1e30f, lrun = 0.f;
    // prime K registers for chunk 0
    bf16x8 k0[4], k1[4];
#pragma unroll
    for (int t = 0; t < 4; t++) {
        const size_t krow = (size_t)(t * 16 + lr) * 512 + hi * 8;
        k0[t] = *(const bf16x8*)&Kp[krow];
        k1[t] = *(const bf16x8*)&Kp[krow + 32];
    }
    for (int kc = 0; kc < 1024; kc += 64) {
        bf16x8 n0[4], n1[4];
        if (kc < 960) {
#pragma unroll
            for (int t = 0; t < 4; t++) {
                const size_t krow = (size_t)(kc + 64 + t * 16 + lr) * 512 + hi * 8;
                n0[t] = *(const bf16x8*)&Kp[krow];
                n1[t] = *(const bf16x8*)&Kp[krow + 32];
            }
        }
        f32x4 st[4];
#pragma unroll
        for (int t = 0; t < 4; t++) {
#pragma unroll
            for (int e = 0; e < 4; e++) st[t][e] = 0.f;
            st[t] = mfma32(k0[t], qf0, st[t]);
            st[t] = mfma32(k1[t], qf1, st[t]);
        }
        float mx = -1e30f;
#pragma unroll
        for (int t = 0; t < 4; t++)
#pragma unroll
            for (int j = 0; j < 4; j++) mx = fmaxf(mx, st[t][j]);
        mx = fmaxf(mx, __shfl_xor(mx, 16));
        mx = fmaxf(mx, __shfl_xor(mx, 32));
        if (!__all(mx - mrun <= 8.f)) {             // defer-max (T13)
            const float mnew = fmaxf(mrun, mx);
            const float alpha = __expf(mrun - mnew);
            lrun *= alpha;
#pragma unroll
            for (int dj = 0; dj < 4; dj++)
#pragma unroll
                for (int e = 0; e < 4; e++) accO[dj][e] *= alpha;
            mrun = mnew;
        }
        float ps = 0.f;
        unsigned P64[4][2];               // per t: packed bf16 x4 (j=0..3)
#pragma unroll
        for (int t = 0; t < 4; t++) {
            const float p0 = __expf(st[t][0] - mrun);
            const float p1 = __expf(st[t][1] - mrun);
            const float p2 = __expf(st[t][2] - mrun);
            const float p3 = __expf(st[t][3] - mrun);
            ps += (p0 + p1) + (p2 + p3);
            P64[t][0] = (unsigned)f2b(p0) | ((unsigned)f2b(p1) << 16);
            P64[t][1] = (unsigned)f2b(p2) | ((unsigned)f2b(p3) << 16);
        }
        ps += __shfl_xor(ps, 16);
        ps += __shfl_xor(ps, 32);
        lrun += ps;
        // build P fragments for the two 32-wide subtiles
        bf16x8 pfrag[2];
#pragma unroll
        for (int ks = 0; ks < 2; ks++) {
            const unsigned c0x = P64[ks * 2 + 0][0], c0y = P64[ks * 2 + 0][1];
            const unsigned c1x = P64[ks * 2 + 1][0], c1y = P64[ks * 2 + 1][1];
            const unsigned a0x = (unsigned)__shfl((int)c0x, srcA);
            const unsigned a0y = (unsigned)__shfl((int)c0y, srcA);
            const unsigned a1x = (unsigned)__shfl((int)c1x, srcA);
            const unsigned a1y = (unsigned)__shfl((int)c1y, srcA);
            const unsigned b0x = (unsigned)__shfl((int)c0x, srcB);
            const unsigned b0y = (unsigned)__shfl((int)c0y, srcB);
            const unsigned b1x = (unsigned)__shfl((int)c1x, srcB);
            const unsigned b1y = (unsigned)__shfl((int)c1y, srcB);
            union { unsigned u[4]; bf16x8 v; } pk;
            pk.u[0] = up ? a1x : a0x;
            pk.u[1] = up ? a1y : a0y;
            pk.u[2] = up ? b1x : b0x;
            pk.u[3] = up ? b1y : b0y;
            pfrag[ks] = pk.v;
        }
#pragma unroll
        for (int dj = 0; dj < 4; dj++)
#pragma unroll
            for (int ks = 0; ks < 2; ks++) {
                const bf16x8 vf = *(const bf16x8*)
                    &Vp[(size_t)(dj * 16 + lr) * 1024 + kc + ks * 32 + hi * 8];
                accO[dj] = mfma32(vf, pfrag[ks], accO[dj]);
            }
        if (kc < 960) {
#pragma unroll
            for (int t = 0; t < 4; t++) { k0[t] = n0[t]; k1[t] = n1[t]; }
        }
    }
    const float invl = 1.f / lrun;
#pragma unroll
    for (int dj = 0; dj < 4; dj++) {
        const int d0 = dj * 16 + hi * 4;
        float y[4];
#pragma unroll
        for (int pp = 0; pp < 2; pp++) {
            const float x0 = accO[dj][2 * pp] * invl;
            const float x1 = accO[dj][2 * pp + 1] * invl;
            const int ii = (d0 >> 1) + pp;
            if (ii < 16) {
                const float cc = tab[((size_t)qr << 5) + (ii << 1)];
                const float ss = tab[((size_t)qr << 5) + (ii << 1) + 1];
                y[2 * pp]     = fmaf(x0, cc, x1 * ss);    // inverse rotation
                y[2 * pp + 1] = fmaf(x1, cc, -x0 * ss);
            } else {
                y[2 * pp] = x0; y[2 * pp + 1] = x1;
            }
        }
        ushort4 o;
        o.x = f2b(y[0]); o.y = f2b(y[1]); o.z = f2b(y[2]); o.w = f2b(y[3]);
        *(ushort4*)&ao[(size_t)qr * 512 + h * 64 + d0] = o;
    }
}

// ---------------- final: LN + dot with wproj (bf16 in, f32 out) -------------
__global__ __launch_bounds__(128) void k_final(
    const u16* __restrict__ dec, const float* __restrict__ w,
    const float* __restrict__ bb, const float* __restrict__ wproj,
    const float* __restrict__ bproj, float* __restrict__ out)
{
    const int r = blockIdx.x, tid = threadIdx.x, c0 = tid << 2;
    const ushort4 xi = *(const ushort4*)&dec[(size_t)r * 512 + c0];
    float4 x;
    x.x = b2f(xi.x); x.y = b2f(xi.y); x.z = b2f(xi.z); x.w = b2f(xi.w);
    float s  = x.x + x.y + x.z + x.w;
    float s2 = x.x * x.x + x.y * x.y + x.z * x.z + x.w * x.w;
#pragma unroll
    for (int o = 32; o > 0; o >>= 1) { s += __shfl_down(s, o); s2 += __shfl_down(s2, o); }
    __shared__ float buf[4];
    if ((tid & 63) == 0) { buf[(tid >> 6) << 1] = s; buf[((tid >> 6) << 1) + 1] = s2; }
    __syncthreads();
    s = buf[0] + buf[2]; s2 = buf[1] + buf[3];
    const float mu = s * (1.f / 512.f);
    const float rs = rsqrtf(s2 * (1.f / 512.f) - mu * mu + 1e-5f);
    const float4 w4 = *(const float4*)&w[c0];
    const float4 b4 = *(const float4*)&bb[c0];
    const float4 p4 = *(const float4*)&wproj[c0];
    float part = ((x.x - mu) * rs * w4.x + b4.x) * p4.x
               + ((x.y - mu) * rs * w4.y + b4.y) * p4.y
               + ((x.z - mu) * rs * w4.z + b4.z) * p4.z
               + ((x.w - mu) * rs * w4.w + b4.w) * p4.w;
#pragma unroll
    for (int o = 32; o > 0; o >>= 1) part += __shfl_down(part, o);
    __shared__ float buf2[2];
    if ((tid & 63) == 0) buf2[tid >> 6] = part;
    __syncthreads();
    if (tid == 0) out[r] = buf2[0] + buf2[1] + bproj[0];
}

// ---------------------------------------------------------------------------
extern "C" void kernel_launch(void* const* d_in, const int* in_sizes, int n_in,
                              void* d_out, int out_size, void* d_ws, size_t ws_size,
                              hipStream_t stream)
{
    (void)in_sizes; (void)n_in; (void)out_size;
    const float* enc  = (const float*)d_in[0];
    const float* lts  = (const float*)d_in[1];
    const int*   qidx = (const int*)  d_in[2];
    const float* qts  = (const float*)d_in[3];
    const float* uemb = (const float*)d_in[4];
    const float* vpb  = (const float*)d_in[6];
    const float* canw = (const float*)d_in[7];
    const float* canb = (const float*)d_in[8];
    const float* ccw  = (const float*)d_in[9];
    const float* ccb  = (const float*)d_in[10];
    const float* wq   = (const float*)d_in[11];
    const float* wkv  = (const float*)d_in[12];
    const float* wo   = (const float*)d_in[13];
    const float* bo   = (const float*)d_in[14];
    const float* flnw = (const float*)d_in[15];
    const float* flnb = (const float*)d_in[16];
    const float* w1   = (const float*)d_in[17];
    const float* b1   = (const float*)d_in[18];
    const float* w2   = (const float*)d_in[19];
    const float* b2   = (const float*)d_in[20];
    const float* olnw = (const float*)d_in[21];
    const float* olnb = (const float*)d_in[22];
    const float* wpj  = (const float*)d_in[23];
    const float* bpj  = (const float*)d_in[24];
    float* outp = (float*)d_out;

    // workspace: f32 tabs, then bf16 region
    float* tabq = (float*)d_ws;              // 16384*32
    float* tabl = tabq + 524288;             // 4096*32
    u16* wqb  = (u16*)(tabl + 131072);       // 512*512
    u16* wkvb = wqb + 262144;                // 1024*512
    u16* wob  = wkvb + 524288;               // 512*512
    u16* w1b  = wob + 262144;                // 4096*512
    u16* w2b  = w1b + 2097152;               // 512*2048
    u16* cn   = w2b + 1048576;               // 4096*512
    u16* kb   = cn + 2097152;                // 4096*512
    u16* vT   = kb + 2097152;                // 4*8*64*1024
    const size_t base_b = 2621440ull + 20971520ull;       // tabs + bf16 shared
    int CQ = 16384;
    while (CQ > 512 &&
           base_b + (size_t)CQ * 5120 + (size_t)(CQ < 4096 ? CQ : 4096) * 4096 > ws_size)
        CQ >>= 1;
    int SF = CQ;
    while (SF > 512 && base_b + (size_t)CQ * 5120 + (size_t)SF * 4096 > ws_size)
        SF >>= 1;
    u16* qtokC = vT + 2097152;               // CQ*512
    u16* xnC   = qtokC + (size_t)CQ * 512;   // CQ*512 (reused: ln_dec)
    u16* qC    = xnC + (size_t)CQ * 512;     // CQ*512 (reused: dec_final)
    u16* aoC   = qC + (size_t)CQ * 512;      // CQ*512
    u16* d2C   = aoC + (size_t)CQ * 512;     // CQ*512
    u16* agC   = d2C + (size_t)CQ * 512;     // SF*2048

    k_cvt<<<256, 256, 0, stream>>>(wq, wqb, 262144);
    k_cvt<<<512, 256, 0, stream>>>(wkv, wkvb, 524288);
    k_cvt<<<256, 256, 0, stream>>>(wo, wob, 262144);
    k_cvt<<<2048, 256, 0, stream>>>(w1, w1b, 2097152);
    k_cvt<<<1024, 256, 0, stream>>>(w2, w2b, 1048576);
    k_rope_tab16<<<1024, 256, 0, stream>>>(qts, tabq, 16384);
    k_rope_tab16<<<256, 256, 0, stream>>>(lts, tabl, 4096);
    k_ln_f<<<4096, 128, 0, stream>>>(enc, ccw, ccb, cn);
    k_mgemm<1><<<dim3(8, 32), 256, 0, stream>>>(cn, wkvb, 1024, 512,
                                                kb, vT, nullptr, nullptr, tabl);

    for (int g0 = 0; g0 < 16384; g0 += CQ) {
        const float* tabc = tabq + (size_t)g0 * 32;
        k_qtok_ln<<<CQ, 128, 0, stream>>>(qidx + g0, uemb, vpb, canw, canb,
                                          qtokC, xnC);
        k_mgemm<0><<<dim3(4, CQ / 128), 256, 0, stream>>>(xnC, wqb, 512, 512,
                                                          qC, nullptr, nullptr, nullptr, tabc);
        k_mattn<<<dim3(CQ / 64, 8), 256, 0, stream>>>(qC, kb, vT, tabc, aoC, g0);
        k_mgemm<2><<<dim3(4, CQ / 128), 256, 0, stream>>>(aoC, wob, 512, 512,
                                                          d2C, nullptr, bo, qtokC, nullptr);
        k_ln_h<<<CQ, 128, 0, stream>>>(d2C, flnw, flnb, xnC);
        for (int f0 = 0; f0 < CQ; f0 += SF) {
            k_mffn1<<<dim3(32, SF / 128), 256, 0, stream>>>(xnC + (size_t)f0 * 512,
                                                            w1b, b1, agC);
            k_mgemm<2><<<dim3(4, SF / 128), 256, 0, stream>>>(agC, w2b, 512, 2048,
                                                              qC + (size_t)f0 * 512, nullptr,
                                                              b2, d2C + (size_t)f0 * 512, nullptr);
            k_final<<<SF, 128, 0, stream>>>(qC + (size_t)f0 * 512, olnw, olnb,
                                            wpj, bpj, outp + g0 + f0);
        }
    }
}

// Round 10
// 411.766 us; speedup vs baseline: 7.2713x; 1.2451x over previous
//
#include <hip/hip_runtime.h>
#include <math.h>

// ---------------------------------------------------------------------------
// MaskingDecoder bf16-MFMA v8: r9 + attention L2-locality attack:
//   - XCD-aware 1D grid: head = blockIdx.x & 7 -> all blocks of a head share
//     one XCD, K+V (1MB) becomes L2-resident
//   - QBLK=128: two q-groups per wave share every K and V load (traffic /2,
//     ILP x2). K register prefetch dropped (freed VGPRs).
// GEMMs byte-identical to r9.
// ---------------------------------------------------------------------------

typedef unsigned short u16;
typedef __attribute__((ext_vector_type(8))) short bf16x8;
typedef __attribute__((ext_vector_type(4))) float f32x4;

__device__ __forceinline__ u16 f2b(float x) {
    union { float f; unsigned u; } v; v.f = x;
    unsigned r = v.u + 0x7fffu + ((v.u >> 16) & 1u);
    return (u16)(r >> 16);
}
__device__ __forceinline__ float b2f(u16 h) {
    union { unsigned u; float f; } v; v.u = ((unsigned)h) << 16;
    return v.f;
}
__device__ __forceinline__ f32x4 mfma32(bf16x8 a, bf16x8 b, f32x4 c) {
    return __builtin_amdgcn_mfma_f32_16x16x32_bf16(a, b, c, 0, 0, 0);
}

// ---------------- f32 -> bf16 weight convert --------------------------------
__global__ __launch_bounds__(256) void k_cvt(const float* __restrict__ in,
                                             u16* __restrict__ out, const int n)
{
    const int i = (blockIdx.x * 256 + threadIdx.x) * 4;
    if (i >= n) return;
    const float4 v = *(const float4*)&in[i];
    ushort4 o;
    o.x = f2b(v.x); o.y = f2b(v.y); o.z = f2b(v.z); o.w = f2b(v.w);
    *(ushort4*)&out[i] = o;
}

// ---------------- rope table: 16 (cos,sin) pairs per row --------------------
__global__ void k_rope_tab16(const float* __restrict__ t, float* __restrict__ tab,
                             const int n)
{
    const int idx = blockIdx.x * 256 + threadIdx.x;
    if (idx >= n * 16) return;
    const int r = idx >> 4, i = idx & 15;
    const float b0 = (float)(1e-4 / 2.0627);
    const float a0 = (float)(2.0 * 3.14159265358979323846 / 1e-4);
    const float invf = a0 * (float)pow((double)b0, (double)i * (1.0 / 16.0));
    const float ang = t[r] * invf;
    float sn, cs;
    sincosf(ang, &sn, &cs);
    tab[((size_t)r << 5) + (i << 1)]     = cs;
    tab[((size_t)r << 5) + (i << 1) + 1] = sn;
}

// ---------------- qtok build + layernorm -> bf16 ----------------------------
__global__ __launch_bounds__(128) void k_qtok_ln(
    const int* __restrict__ qidx, const float* __restrict__ uemb,
    const float* __restrict__ vpb, const float* __restrict__ w,
    const float* __restrict__ bb, u16* __restrict__ qtok, u16* __restrict__ xn)
{
    const int r = blockIdx.x, tid = threadIdx.x, c0 = tid << 2;
    float4 x;
    if (c0 < 256) {
        x = *(const float4*)&vpb[c0];
    } else {
        const int u = qidx[r];
        x = *(const float4*)&uemb[(size_t)u * 256 + (c0 - 256)];
    }
    ushort4 qo;
    qo.x = f2b(x.x); qo.y = f2b(x.y); qo.z = f2b(x.z); qo.w = f2b(x.w);
    *(ushort4*)&qtok[(size_t)r * 512 + c0] = qo;
    float s  = x.x + x.y + x.z + x.w;
    float s2 = x.x * x.x + x.y * x.y + x.z * x.z + x.w * x.w;
#pragma unroll
    for (int o = 32; o > 0; o >>= 1) { s += __shfl_down(s, o); s2 += __shfl_down(s2, o); }
    __shared__ float buf[4];
    if ((tid & 63) == 0) { buf[(tid >> 6) << 1] = s; buf[((tid >> 6) << 1) + 1] = s2; }
    __syncthreads();
    s = buf[0] + buf[2]; s2 = buf[1] + buf[3];
    const float mu = s * (1.f / 512.f);
    const float rs = rsqrtf(s2 * (1.f / 512.f) - mu * mu + 1e-5f);
    const float4 w4 = *(const float4*)&w[c0];
    const float4 b4 = *(const float4*)&bb[c0];
    ushort4 yo;
    yo.x = f2b((x.x - mu) * rs * w4.x + b4.x);
    yo.y = f2b((x.y - mu) * rs * w4.y + b4.y);
    yo.z = f2b((x.z - mu) * rs * w4.z + b4.z);
    yo.w = f2b((x.w - mu) * rs * w4.w + b4.w);
    *(ushort4*)&xn[(size_t)r * 512 + c0] = yo;
}

// ---------------- layernorm f32-in -> bf16-out ------------------------------
__global__ __launch_bounds__(128) void k_ln_f(
    const float* __restrict__ in, const float* __restrict__ w,
    const float* __restrict__ bb, u16* __restrict__ outp)
{
    const int r = blockIdx.x, tid = threadIdx.x, c0 = tid << 2;
    const float4 x = *(const float4*)&in[(size_t)r * 512 + c0];
    float s  = x.x + x.y + x.z + x.w;
    float s2 = x.x * x.x + x.y * x.y + x.z * x.z + x.w * x.w;
#pragma unroll
    for (int o = 32; o > 0; o >>= 1) { s += __shfl_down(s, o); s2 += __shfl_down(s2, o); }
    __shared__ float buf[4];
    if ((tid & 63) == 0) { buf[(tid >> 6) << 1] = s; buf[((tid >> 6) << 1) + 1] = s2; }
    __syncthreads();
    s = buf[0] + buf[2]; s2 = buf[1] + buf[3];
    const float mu = s * (1.f / 512.f);
    const float rs = rsqrtf(s2 * (1.f / 512.f) - mu * mu + 1e-5f);
    const float4 w4 = *(const float4*)&w[c0];
    const float4 b4 = *(const float4*)&bb[c0];
    ushort4 yo;
    yo.x = f2b((x.x - mu) * rs * w4.x + b4.x);
    yo.y = f2b((x.y - mu) * rs * w4.y + b4.y);
    yo.z = f2b((x.z - mu) * rs * w4.z + b4.z);
    yo.w = f2b((x.w - mu) * rs * w4.w + b4.w);
    *(ushort4*)&outp[(size_t)r * 512 + c0] = yo;
}

// ---------------- layernorm bf16-in -> bf16-out -----------------------------
__global__ __launch_bounds__(128) void k_ln_h(
    const u16* __restrict__ in, const float* __restrict__ w,
    const float* __restrict__ bb, u16* __restrict__ outp)
{
    const int r = blockIdx.x, tid = threadIdx.x, c0 = tid << 2;
    const ushort4 xi = *(const ushort4*)&in[(size_t)r * 512 + c0];
    float4 x;
    x.x = b2f(xi.x); x.y = b2f(xi.y); x.z = b2f(xi.z); x.w = b2f(xi.w);
    float s  = x.x + x.y + x.z + x.w;
    float s2 = x.x * x.x + x.y * x.y + x.z * x.z + x.w * x.w;
#pragma unroll
    for (int o = 32; o > 0; o >>= 1) { s += __shfl_down(s, o); s2 += __shfl_down(s2, o); }
    __shared__ float buf[4];
    if ((tid & 63) == 0) { buf[(tid >> 6) << 1] = s; buf[((tid >> 6) << 1) + 1] = s2; }
    __syncthreads();
    s = buf[0] + buf[2]; s2 = buf[1] + buf[3];
    const float mu = s * (1.f / 512.f);
    const float rs = rsqrtf(s2 * (1.f / 512.f) - mu * mu + 1e-5f);
    const float4 w4 = *(const float4*)&w[c0];
    const float4 b4 = *(const float4*)&bb[c0];
    ushort4 yo;
    yo.x = f2b((x.x - mu) * rs * w4.x + b4.x);
    yo.y = f2b((x.y - mu) * rs * w4.y + b4.y);
    yo.z = f2b((x.z - mu) * rs * w4.z + b4.z);
    yo.w = f2b((x.w - mu) * rs * w4.w + b4.w);
    *(ushort4*)&outp[(size_t)r * 512 + c0] = yo;
}

// ---------------- MFMA GEMM: C[m,n] = sum_k A[m,k]*W[n,k] -------------------
// 128x128 tile, BK=32, 4 waves (2x2), register-staged LDS (r3-proven).
// EPI 0: rope(tab) -> out0 bf16
// EPI 1: rope(tab); c<512 -> out0 (k, pre-scaled by 1/8); c>=512 -> out1 (vT)
// EPI 2: out0 = acc + bias + res (bf16 residual add)
template <int EPI>
__global__ __launch_bounds__(256) void k_mgemm(
    const u16* __restrict__ A, const u16* __restrict__ W,
    const int N, const int K,
    u16* __restrict__ out0, u16* __restrict__ out1,
    const float* __restrict__ bias, const u16* __restrict__ res,
    const float* __restrict__ tab)
{
    __shared__ u16 Al[128 * 32];
    __shared__ u16 Bl[128 * 32];
    const int bm = blockIdx.y << 7, bn = blockIdx.x << 7;
    const int tid = threadIdx.x;
    const int w = tid >> 6, l = tid & 63;
    const int wm = w >> 1, wn = w & 1;
    const int srow = tid >> 2, skq = (tid & 3) << 3;
    const int lr = l & 15, hi = l >> 4;
    const u16* Ap = A + (size_t)(bm + srow) * K + skq;
    const u16* Wp = W + (size_t)(bn + srow) * K + skq;
    f32x4 acc[4][4];
#pragma unroll
    for (int i = 0; i < 4; i++)
#pragma unroll
        for (int j = 0; j < 4; j++)
#pragma unroll
            for (int e = 0; e < 4; e++) acc[i][j][e] = 0.f;
    for (int k0 = 0; k0 < K; k0 += 32) {
        const uint4 a0 = *(const uint4*)(Ap + k0);
        const uint4 a1 = *(const uint4*)(Ap + (size_t)64 * K + k0);
        const uint4 b0 = *(const uint4*)(Wp + k0);
        const uint4 b1 = *(const uint4*)(Wp + (size_t)64 * K + k0);
        __syncthreads();
        *(uint4*)&Al[srow * 32 + skq] = a0;
        *(uint4*)&Al[(srow + 64) * 32 + skq] = a1;
        *(uint4*)&Bl[srow * 32 + skq] = b0;
        *(uint4*)&Bl[(srow + 64) * 32 + skq] = b1;
        __syncthreads();
        bf16x8 av[4], bv[4];
#pragma unroll
        for (int mi = 0; mi < 4; mi++)
            av[mi] = *(const bf16x8*)&Al[(wm * 64 + mi * 16 + lr) * 32 + hi * 8];
#pragma unroll
        for (int nj = 0; nj < 4; nj++)
            bv[nj] = *(const bf16x8*)&Bl[(wn * 64 + nj * 16 + lr) * 32 + hi * 8];
#pragma unroll
        for (int mi = 0; mi < 4; mi++)
#pragma unroll
            for (int nj = 0; nj < 4; nj++)
                acc[mi][nj] = mfma32(av[mi], bv[nj], acc[mi][nj]);
    }
#pragma unroll
    for (int mi = 0; mi < 4; mi++) {
#pragma unroll
        for (int nj = 0; nj < 4; nj++) {
            const int c = bn + wn * 64 + nj * 16 + lr;
#pragma unroll
            for (int j = 0; j < 4; j++) {
                const int r = bm + wm * 64 + mi * 16 + hi * 4 + j;
                const float x = acc[mi][nj][j];
                if (EPI == 2) {
                    const float y = x + bias[c] + b2f(res[(size_t)r * 512 + c]);
                    out0[(size_t)r * 512 + c] = f2b(y);
                } else {
                    const float p = __shfl_xor(x, 1);
                    const int ci = c & 63;
                    float y = x;
                    if (ci < 32) {
                        const int ii = ci >> 1;
                        const float cc = tab[((size_t)r << 5) + (ii << 1)];
                        const float ss = tab[((size_t)r << 5) + (ii << 1) + 1];
                        y = (c & 1) ? fmaf(x, cc, p * ss) : fmaf(x, cc, -p * ss);
                    }
                    if (EPI == 0) {
                        out0[(size_t)r * 512 + c] = f2b(y);
                    } else {
                        if (c < 512) {
                            out0[(size_t)r * 512 + c] = f2b(y * 0.125f);  // fold DH^-0.5
                        } else {
                            const int d = c - 512, hh = d >> 6, dd = d & 63;
                            const int bq = r >> 10, pos = r & 1023;
                            out1[(((size_t)(bq * 8 + hh)) * 64 + dd) * 1024 + pos] = f2b(y);
                        }
                    }
                }
            }
        }
    }
}

// ---------------- FFN1: dual MFMA GEMM + exact gelu gate --------------------
__global__ __launch_bounds__(256) void k_mffn1(
    const u16* __restrict__ A, const u16* __restrict__ W1,
    const float* __restrict__ b1, u16* __restrict__ ag)
{
    __shared__ u16 Al[128 * 32];
    __shared__ u16 Bl[128 * 32];
    const int bm = blockIdx.y << 7, bn = blockIdx.x << 6;
    const int tid = threadIdx.x;
    const int w = tid >> 6, l = tid & 63;
    const int wm = w >> 1, wn = w & 1;
    const int srow = tid >> 2, skq = (tid & 3) << 3;
    const int lr = l & 15, hi = l >> 4;
    const u16* Ap  = A  + (size_t)(bm + srow) * 512 + skq;
    const u16* Wap = W1 + (size_t)(bn + srow) * 512 + skq;
    const u16* Wgp = W1 + (size_t)(2048 + bn + srow) * 512 + skq;
    f32x4 acca[4][2], accg[4][2];
#pragma unroll
    for (int i = 0; i < 4; i++)
#pragma unroll
        for (int j = 0; j < 2; j++)
#pragma unroll
            for (int e = 0; e < 4; e++) { acca[i][j][e] = 0.f; accg[i][j][e] = 0.f; }
    for (int k0 = 0; k0 < 512; k0 += 32) {
        const uint4 a0 = *(const uint4*)(Ap + k0);
        const uint4 a1 = *(const uint4*)(Ap + (size_t)64 * 512 + k0);
        const uint4 w0 = *(const uint4*)(Wap + k0);
        const uint4 w1v = *(const uint4*)(Wgp + k0);
        __syncthreads();
        *(uint4*)&Al[srow * 32 + skq] = a0;
        *(uint4*)&Al[(srow + 64) * 32 + skq] = a1;
        *(uint4*)&Bl[srow * 32 + skq] = w0;
        *(uint4*)&Bl[(srow + 64) * 32 + skq] = w1v;
        __syncthreads();
        bf16x8 av[4], ba[2], bg[2];
#pragma unroll
        for (int mi = 0; mi < 4; mi++)
            av[mi] = *(const bf16x8*)&Al[(wm * 64 + mi * 16 + lr) * 32 + hi * 8];
#pragma unroll
        for (int nj = 0; nj < 2; nj++) {
            ba[nj] = *(const bf16x8*)&Bl[(wn * 32 + nj * 16 + lr) * 32 + hi * 8];
            bg[nj] = *(const bf16x8*)&Bl[(wn * 32 + nj * 16 + lr + 64) * 32 + hi * 8];
        }
#pragma unroll
        for (int mi = 0; mi < 4; mi++)
#pragma unroll
            for (int nj = 0; nj < 2; nj++) {
                acca[mi][nj] = mfma32(av[mi], ba[nj], acca[mi][nj]);
                accg[mi][nj] = mfma32(av[mi], bg[nj], accg[mi][nj]);
            }
    }
#pragma unroll
    for (int mi = 0; mi < 4; mi++)
#pragma unroll
        for (int nj = 0; nj < 2; nj++) {
            const int c = bn + wn * 32 + nj * 16 + lr;
#pragma unroll
            for (int j = 0; j < 4; j++) {
                const int r = bm + wm * 64 + mi * 16 + hi * 4 + j;
                const float a = acca[mi][nj][j] + b1[c];
                const float g = accg[mi][nj][j] + b1[2048 + c];
                const float ge = 0.5f * g * (1.f + erff(g * 0.70710678118654752f));
                ag[(size_t)r * 2048 + c] = f2b(a * ge);
            }
        }
}

// ---------------- attention: XCD-local, dual q-group, shared K/V loads ------
// 1D grid NB=(CQ/128)*8: head = bid&7 (-> XCD-local K/V), qchunk = bid>>3.
// 256 thr = 4 waves; wave owns 32 q rows = two 16-row groups A(qrA) B(qrA+16)
// sharing all K and V loads. K pre-scaled by 1/8. Defer-max; __expf.
__global__ __launch_bounds__(256) void k_mattn(
    const u16* __restrict__ q, const u16* __restrict__ kbuf,
    const u16* __restrict__ vT, const float* __restrict__ tab,
    u16* __restrict__ ao, const int rowbase)
{
    const int bid = blockIdx.x, tid = threadIdx.x;
    const int h = bid & 7, qi = bid >> 3;
    const int qbase = qi << 7;
    const int w = tid >> 6, l = tid & 63;
    const int lr = l & 15, hi = l >> 4;
    const int qrA = qbase + w * 32 + lr;
    const int qrB = qrA + 16;
    const int b = (rowbase + qbase) >> 12;              // batch
    const bf16x8 qfA0 = *(const bf16x8*)&q[(size_t)qrA * 512 + h * 64 + hi * 8];
    const bf16x8 qfA1 = *(const bf16x8*)&q[(size_t)qrA * 512 + h * 64 + hi * 8 + 32];
    const bf16x8 qfB0 = *(const bf16x8*)&q[(size_t)qrB * 512 + h * 64 + hi * 8];
    const bf16x8 qfB1 = *(const bf16x8*)&q[(size_t)qrB * 512 + h * 64 + hi * 8 + 32];
    const u16* Kp = kbuf + (size_t)b * 524288 + h * 64;
    const u16* Vp = vT + ((size_t)(b * 8 + h)) * 65536;
    const int g2 = (hi & 1) * 2;
    const int srcA = lr + (g2 << 4);
    const int srcB = srcA + 16;
    const bool up = (hi >> 1) != 0;
    f32x4 accA[4], accB[4];
#pragma unroll
    for (int dj = 0; dj < 4; dj++)
#pragma unroll
        for (int e = 0; e < 4; e++) { accA[dj][e] = 0.f; accB[dj][e] = 0.f; }
    float mA = -1e30f, lA = 0.f, mB = -1e30f, lB = 0.f;
    for (int kc = 0; kc < 1024; kc += 64) {
        f32x4 stA[4], stB[4];
#pragma unroll
        for (int t = 0; t < 4; t++) {
            const size_t krow = (size_t)(kc + t * 16 + lr) * 512 + hi * 8;
            const bf16x8 kf0 = *(const bf16x8*)&Kp[krow];
            const bf16x8 kf1 = *(const bf16x8*)&Kp[krow + 32];
#pragma unroll
            for (int e = 0; e < 4; e++) { stA[t][e] = 0.f; stB[t][e] = 0.f; }
            stA[t] = mfma32(kf0, qfA0, stA[t]);
            stA[t] = mfma32(kf1, qfA1, stA[t]);
            stB[t] = mfma32(kf0, qfB0, stB[t]);
            stB[t] = mfma32(kf1, qfB1, stB[t]);
        }
        // ---- softmax group A ----
        bf16x8 pfragA[2], pfragB[2];
        {
            float mx = -1e30f;
#pragma unroll
            for (int t = 0; t < 4; t++)
#pragma unroll
                for (int j = 0; j < 4; j++) mx = fmaxf(mx, stA[t][j]);
            mx = fmaxf(mx, __shfl_xor(mx, 16));
            mx = fmaxf(mx, __shfl_xor(mx, 32));
            if (!__all(mx - mA <= 8.f)) {
                const float mnew = fmaxf(mA, mx);
                const float alpha = __expf(mA - mnew);
                lA *= alpha;
#pragma unroll
                for (int dj = 0; dj < 4; dj++)
#pragma unroll
                    for (int e = 0; e < 4; e++) accA[dj][e] *= alpha;
                mA = mnew;
            }
            float ps = 0.f;
            unsigned P64[4][2];
#pragma unroll
            for (int t = 0; t < 4; t++) {
                const float p0 = __expf(stA[t][0] - mA);
                const float p1 = __expf(stA[t][1] - mA);
                const float p2 = __expf(stA[t][2] - mA);
                const float p3 = __expf(stA[t][3] - mA);
                ps += (p0 + p1) + (p2 + p3);
                P64[t][0] = (unsigned)f2b(p0) | ((unsigned)f2b(p1) << 16);
                P64[t][1] = (unsigned)f2b(p2) | ((unsigned)f2b(p3) << 16);
            }
            ps += __shfl_xor(ps, 16);
            ps += __shfl_xor(ps, 32);
            lA += ps;
#pragma unroll
            for (int ks = 0; ks < 2; ks++) {
                const unsigned c0x = P64[ks * 2 + 0][0], c0y = P64[ks * 2 + 0][1];
                const unsigned c1x = P64[ks * 2 + 1][0], c1y = P64[ks * 2 + 1][1];
                const unsigned a0x = (unsigned)__shfl((int)c0x, srcA);
                const unsigned a0y = (unsigned)__shfl((int)c0y, srcA);
                const unsigned a1x = (unsigned)__shfl((int)c1x, srcA);
                const unsigned a1y = (unsigned)__shfl((int)c1y, srcA);
                const unsigned b0x = (unsigned)__shfl((int)c0x, srcB);
                const unsigned b0y = (unsigned)__shfl((int)c0y, srcB);
                const unsigned b1x = (unsigned)__shfl((int)c1x, srcB);
                const unsigned b1y = (unsigned)__shfl((int)c1y, srcB);
                union { unsigned u[4]; bf16x8 v; } pk;
                pk.u[0] = up ? a1x : a0x;
                pk.u[1] = up ? a1y : a0y;
                pk.u[2] = up ? b1x : b0x;
                pk.u[3] = up ? b1y : b0y;
                pfragA[ks] = pk.v;
            }
        }
        // ---- softmax group B ----
        {
            float mx = -1e30f;
#pragma unroll
            for (int t = 0; t < 4; t++)
#pragma unroll
                for (int j = 0; j < 4; j++) mx = fmaxf(mx, stB[t][j]);
            mx = fmaxf(mx, __shfl_xor(mx, 16));
            mx = fmaxf(mx, __shfl_xor(mx, 32));
            if (!__all(mx - mB <= 8.f)) {
                const float mnew = fmaxf(mB, mx);
                const float alpha = __expf(mB - mnew);
                lB *= alpha;
#pragma unroll
                for (int dj = 0; dj < 4; dj++)
#pragma unroll
                    for (int e = 0; e < 4; e++) accB[dj][e] *= alpha;
                mB = mnew;
            }
            float ps = 0.f;
            unsigned P64[4][2];
#pragma unroll
            for (int t = 0; t < 4; t++) {
                const float p0 = __expf(stB[t][0] - mB);
                const float p1 = __expf(stB[t][1] - mB);
                const float p2 = __expf(stB[t][2] - mB);
                const float p3 = __expf(stB[t][3] - mB);
                ps += (p0 + p1) + (p2 + p3);
                P64[t][0] = (unsigned)f2b(p0) | ((unsigned)f2b(p1) << 16);
                P64[t][1] = (unsigned)f2b(p2) | ((unsigned)f2b(p3) << 16);
            }
            ps += __shfl_xor(ps, 16);
            ps += __shfl_xor(ps, 32);
            lB += ps;
#pragma unroll
            for (int ks = 0; ks < 2; ks++) {
                const unsigned c0x = P64[ks * 2 + 0][0], c0y = P64[ks * 2 + 0][1];
                const unsigned c1x = P64[ks * 2 + 1][0], c1y = P64[ks * 2 + 1][1];
                const unsigned a0x = (unsigned)__shfl((int)c0x, srcA);
                const unsigned a0y = (unsigned)__shfl((int)c0y, srcA);
                const unsigned a1x = (unsigned)__shfl((int)c1x, srcA);
                const unsigned a1y = (unsigned)__shfl((int)c1y, srcA);
                const unsigned b0x = (unsigned)__shfl((int)c0x, srcB);
                const unsigned b0y = (unsigned)__shfl((int)c0y, srcB);
                const unsigned b1x = (unsigned)__shfl((int)c1x, srcB);
                const unsigned b1y = (unsigned)__shfl((int)c1y, srcB);
                union { unsigned u[4]; bf16x8 v; } pk;
                pk.u[0] = up ? a1x : a0x;
                pk.u[1] = up ? a1y : a0y;
                pk.u[2] = up ? b1x : b0x;
                pk.u[3] = up ? b1y : b0y;
                pfragB[ks] = pk.v;
            }
        }
        // ---- PV: shared V loads feed both groups ----
#pragma unroll
        for (int dj = 0; dj < 4; dj++)
#pragma unroll
            for (int ks = 0; ks < 2; ks++) {
                const bf16x8 vf = *(const bf16x8*)
                    &Vp[(size_t)(dj * 16 + lr) * 1024 + kc + ks * 32 + hi * 8];
                accA[dj] = mfma32(vf, pfragA[ks], accA[dj]);
                accB[dj] = mfma32(vf, pfragB[ks], accB[dj]);
            }
    }
    const float ivA = 1.f / lA, ivB = 1.f / lB;
#pragma unroll
    for (int g = 0; g < 2; g++) {
        const int qr = g ? qrB : qrA;
        const float invl = g ? ivB : ivA;
#pragma unroll
        for (int dj = 0; dj < 4; dj++) {
            const f32x4 a = g ? accB[dj] : accA[dj];
            const int d0 = dj * 16 + hi * 4;
            float y[4];
#pragma unroll
            for (int pp = 0; pp < 2; pp++) {
                const float x0 = a[2 * pp] * invl;
                const float x1 = a[2 * pp + 1] * invl;
                const int ii = (d0 >> 1) + pp;
                if (ii < 16) {
                    const float cc = tab[((size_t)qr << 5) + (ii << 1)];
                    const float ss = tab[((size_t)qr << 5) + (ii << 1) + 1];
                    y[2 * pp]     = fmaf(x0, cc, x1 * ss);    // inverse rotation
                    y[2 * pp + 1] = fmaf(x1, cc, -x0 * ss);
                } else {
                    y[2 * pp] = x0; y[2 * pp + 1] = x1;
                }
            }
            ushort4 o;
            o.x = f2b(y[0]); o.y = f2b(y[1]); o.z = f2b(y[2]); o.w = f2b(y[3]);
            *(ushort4*)&ao[(size_t)qr * 512 + h * 64 + d0] = o;
        }
    }
}

// ---------------- final: LN + dot with wproj (bf16 in, f32 out) -------------
__global__ __launch_bounds__(128) void k_final(
    const u16* __restrict__ dec, const float* __restrict__ w,
    const float* __restrict__ bb, const float* __restrict__ wproj,
    const float* __restrict__ bproj, float* __restrict__ out)
{
    const int r = blockIdx.x, tid = threadIdx.x, c0 = tid << 2;
    const ushort4 xi = *(const ushort4*)&dec[(size_t)r * 512 + c0];
    float4 x;
    x.x = b2f(xi.x); x.y = b2f(xi.y); x.z = b2f(xi.z); x.w = b2f(xi.w);
    float s  = x.x + x.y + x.z + x.w;
    float s2 = x.x * x.x + x.y * x.y + x.z * x.z + x.w * x.w;
#pragma unroll
    for (int o = 32; o > 0; o >>= 1) { s += __shfl_down(s, o); s2 += __shfl_down(s2, o); }
    __shared__ float buf[4];
    if ((tid & 63) == 0) { buf[(tid >> 6) << 1] = s; buf[((tid >> 6) << 1) + 1] = s2; }
    __syncthreads();
    s = buf[0] + buf[2]; s2 = buf[1] + buf[3];
    const float mu = s * (1.f / 512.f);
    const float rs = rsqrtf(s2 * (1.f / 512.f) - mu * mu + 1e-5f);
    const float4 w4 = *(const float4*)&w[c0];
    const float4 b4 = *(const float4*)&bb[c0];
    const float4 p4 = *(const float4*)&wproj[c0];
    float part = ((x.x - mu) * rs * w4.x + b4.x) * p4.x
               + ((x.y - mu) * rs * w4.y + b4.y) * p4.y
               + ((x.z - mu) * rs * w4.z + b4.z) * p4.z
               + ((x.w - mu) * rs * w4.w + b4.w) * p4.w;
#pragma unroll
    for (int o = 32; o > 0; o >>= 1) part += __shfl_down(part, o);
    __shared__ float buf2[2];
    if ((tid & 63) == 0) buf2[tid >> 6] = part;
    __syncthreads();
    if (tid == 0) out[r] = buf2[0] + buf2[1] + bproj[0];
}

// ---------------------------------------------------------------------------
extern "C" void kernel_launch(void* const* d_in, const int* in_sizes, int n_in,
                              void* d_out, int out_size, void* d_ws, size_t ws_size,
                              hipStream_t stream)
{
    (void)in_sizes; (void)n_in; (void)out_size;
    const float* enc  = (const float*)d_in[0];
    const float* lts  = (const float*)d_in[1];
    const int*   qidx = (const int*)  d_in[2];
    const float* qts  = (const float*)d_in[3];
    const float* uemb = (const float*)d_in[4];
    const float* vpb  = (const float*)d_in[6];
    const float* canw = (const float*)d_in[7];
    const float* canb = (const float*)d_in[8];
    const float* ccw  = (const float*)d_in[9];
    const float* ccb  = (const float*)d_in[10];
    const float* wq   = (const float*)d_in[11];
    const float* wkv  = (const float*)d_in[12];
    const float* wo   = (const float*)d_in[13];
    const float* bo   = (const float*)d_in[14];
    const float* flnw = (const float*)d_in[15];
    const float* flnb = (const float*)d_in[16];
    const float* w1   = (const float*)d_in[17];
    const float* b1   = (const float*)d_in[18];
    const float* w2   = (const float*)d_in[19];
    const float* b2   = (const float*)d_in[20];
    const float* olnw = (const float*)d_in[21];
    const float* olnb = (const float*)d_in[22];
    const float* wpj  = (const float*)d_in[23];
    const float* bpj  = (const float*)d_in[24];
    float* outp = (float*)d_out;

    // workspace: f32 tabs, then bf16 region
    float* tabq = (float*)d_ws;              // 16384*32
    float* tabl = tabq + 524288;             // 4096*32
    u16* wqb  = (u16*)(tabl + 131072);       // 512*512
    u16* wkvb = wqb + 262144;                // 1024*512
    u16* wob  = wkvb + 524288;               // 512*512
    u16* w1b  = wob + 262144;                // 4096*512
    u16* w2b  = w1b + 2097152;               // 512*2048
    u16* cn   = w2b + 1048576;               // 4096*512
    u16* kb   = cn + 2097152;                // 4096*512
    u16* vT   = kb + 2097152;                // 4*8*64*1024
    const size_t base_b = 2621440ull + 20971520ull;       // tabs + bf16 shared
    int CQ = 16384;
    while (CQ > 512 &&
           base_b + (size_t)CQ * 5120 + (size_t)(CQ < 4096 ? CQ : 4096) * 4096 > ws_size)
        CQ >>= 1;
    int SF = CQ;
    while (SF > 512 && base_b + (size_t)CQ * 5120 + (size_t)SF * 4096 > ws_size)
        SF >>= 1;
    u16* qtokC = vT + 2097152;               // CQ*512
    u16* xnC   = qtokC + (size_t)CQ * 512;   // CQ*512 (reused: ln_dec)
    u16* qC    = xnC + (size_t)CQ * 512;     // CQ*512 (reused: dec_final)
    u16* aoC   = qC + (size_t)CQ * 512;      // CQ*512
    u16* d2C   = aoC + (size_t)CQ * 512;     // CQ*512
    u16* agC   = d2C + (size_t)CQ * 512;     // SF*2048

    k_cvt<<<256, 256, 0, stream>>>(wq, wqb, 262144);
    k_cvt<<<512, 256, 0, stream>>>(wkv, wkvb, 524288);
    k_cvt<<<256, 256, 0, stream>>>(wo, wob, 262144);
    k_cvt<<<2048, 256, 0, stream>>>(w1, w1b, 2097152);
    k_cvt<<<1024, 256, 0, stream>>>(w2, w2b, 1048576);
    k_rope_tab16<<<1024, 256, 0, stream>>>(qts, tabq, 16384);
    k_rope_tab16<<<256, 256, 0, stream>>>(lts, tabl, 4096);
    k_ln_f<<<4096, 128, 0, stream>>>(enc, ccw, ccb, cn);
    k_mgemm<1><<<dim3(8, 32), 256, 0, stream>>>(cn, wkvb, 1024, 512,
                                                kb, vT, nullptr, nullptr, tabl);

    for (int g0 = 0; g0 < 16384; g0 += CQ) {
        const float* tabc = tabq + (size_t)g0 * 32;
        k_qtok_ln<<<CQ, 128, 0, stream>>>(qidx + g0, uemb, vpb, canw, canb,
                                          qtokC, xnC);
        k_mgemm<0><<<dim3(4, CQ / 128), 256, 0, stream>>>(xnC, wqb, 512, 512,
                                                          qC, nullptr, nullptr, nullptr, tabc);
        k_mattn<<<(CQ / 128) * 8, 256, 0, stream>>>(qC, kb, vT, tabc, aoC, g0);
        k_mgemm<2><<<dim3(4, CQ / 128), 256, 0, stream>>>(aoC, wob, 512, 512,
                                                          d2C, nullptr, bo, qtokC, nullptr);
        k_ln_h<<<CQ, 128, 0, stream>>>(d2C, flnw, flnb, xnC);
        for (int f0 = 0; f0 < CQ; f0 += SF) {
            k_mffn1<<<dim3(32, SF / 128), 256, 0, stream>>>(xnC + (size_t)f0 * 512,
                                                            w1b, b1, agC);
            k_mgemm<2><<<dim3(4, SF / 128), 256, 0, stream>>>(agC, w2b, 512, 2048,
                                                              qC + (size_t)f0 * 512, nullptr,
                                                              b2, d2C + (size_t)f0 * 512, nullptr);
            k_final<<<SF, 128, 0, stream>>>(qC + (size_t)f0 * 512, olnw, olnb,
                                            wpj, bpj, outp + g0 + f0);
        }
    }
}